// Round 6
// baseline (402.475 us; speedup 1.0000x reference)
//
#include <hip/hip_runtime.h>
#include <hip/hip_bf16.h>
#include <math.h>

// ---------------------------------------------------------------------------
// PointsToImage: ball-query (K=32, R=0.1) -> PointNetConv msg=[x_j, pos_j-pos_dst]
// -> Linear(66,128) -> masked-BatchNorm -> ReLU -> Linear(128,64) -> scatter-max
// into pixel nodes, output [B=32, F=64, 32, 32] fp32.
//
// R6: eliminate the 2.1M device-scope output atomics (R5: WRITE_SIZE 64 MB).
//  - k_pixmap inverts query->pixel (per-sample LDS count/scan/scatter).
//  - All messages targeting pixel n share t=pos[n]  =>  h = relu(w[src]+shp(n))
//    where w[n]=(y+px*u+py*v)*sc (node-only, bf16, computed in k_self) and
//    shp(n)=sh-(tx*u+ty*v)*sc (pixel-only). Self message == edge src=n (exact
//    cancellation of the t-terms).
//  - k_out: one wave per pixel with >=1 query; streams self+all queries' edges
//    through one MFMA staging buffer; ONE plain store. k_self stores only
//    qcnt==0 nodes. Zero output atomics.
//  - Features re-paired (2l,2l+1): single ds_write_b32 staging, b64 W1 reads,
//    v_cvt_pk_bf16_f32 packing.
// Pipeline: k_prep -> k_pixmap -> k_ballquery -> k_nodeagg -> k_y -> k_finalize
//           -> k_self -> k_out
// ---------------------------------------------------------------------------

#define NPTS   32768
#define KNB    32
#define BN_EPS 1e-5f

// workspace layout (bytes)
#define WS_NBRS     0u           // int[NPTS*KNB]      = 4194304
#define WS_NBRCNT   4194304u     // int[NPTS]          = 131072
#define WS_DEG      4325376u     // float[NPTS]        = 131072
#define WS_STX      4456448u     // float[NPTS]        = 131072
#define WS_STY      4587520u     // float[NPTS]        = 131072
#define WS_DEFREP   4718592u     // float[64*4]        = 1024
#define WS_SCSH     4719616u     // float[256]         = 1024
#define WS_W2B      4720640u     // ushort[8192]       = 16384
#define WS_PART     4737024u     // float[256*516]     = 528384
#define WS_Y        5265408u     // uint[NPTS*64]      = 8388608 (bf16 pairs f=2l,2l+1)
#define WS_BQPART   13654016u    // float[512*3072]    = 6291456 (consumed by k_nodeagg)
#define WS_WB       13654016u    // uint[NPTS*64]      = 8388608 (w, bf16; OVERLAYS bqpart)
#define WS_QCNT     22042624u    // int[NPTS]          = 131072
#define WS_QSTART   22173696u    // int[NPTS]          = 131072
#define WS_QLIST    22304768u    // int[NPTS]          = 131072

typedef __attribute__((ext_vector_type(8))) short short8;
typedef __attribute__((ext_vector_type(4))) float floatx4;

__device__ __forceinline__ unsigned short f2bf(float f) {
    unsigned int u = __float_as_uint(f);
    unsigned int r = u + 0x7fffu + ((u >> 16) & 1u);   // RNE
    return (unsigned short)(r >> 16);
}
__device__ __forceinline__ float bf_lo(unsigned int w) { return __uint_as_float(w << 16); }
__device__ __forceinline__ float bf_hi(unsigned int w) { return __uint_as_float(w & 0xffff0000u); }
__device__ __forceinline__ unsigned int pack_bf2(float lo, float hi) {
    __hip_bfloat162 hh = __float22bfloat162_rn(make_float2(lo, hi));
    return *reinterpret_cast<unsigned int*>(&hh);
}

// ------------------- prep: zero defrep, pack W2 into B-frag bf16 ------------
__global__ void k_prep(const float* __restrict__ W2, unsigned short* __restrict__ w2b,
                       float* __restrict__ defrep) {
    int t = blockIdx.x * 256 + threadIdx.x;     // 32 blocks * 256 = 8192
    if (t < 256) defrep[t] = 0.0f;
    if (t < 8192) {
        int j  = t & 7;
        int L  = (t >> 3) & 63;
        int ks = (t >> 9) & 3;
        int t4 = t >> 11;
        int k = ks * 32 + (L >> 4) * 8 + j;
        int n = t4 * 16 + (L & 15);
        w2b[t] = f2bf(W2[k * 64 + n]);
    }
}

// ------------------- pixel map: invert query -> pixel (per sample) ----------
__launch_bounds__(256)
__global__ void k_pixmap(const float* __restrict__ pos, int* __restrict__ qcnt,
                         int* __restrict__ qstart, int* __restrict__ qlist) {
    __shared__ int cntS[1024], preS[1024], offS[1024], pixOf[1024];
    __shared__ int wtot[4];
    int tid = threadIdx.x;
    int s = blockIdx.x;
    int base = s << 10;
    for (int i = tid; i < 1024; i += 256) cntS[i] = 0;
    __syncthreads();
    for (int ql = tid; ql < 1024; ql += 256) {
        float2 p = *(const float2*)&pos[2 * (base + ql)];
        int row = min(max((int)(p.y * 32.0f), 0), 31);
        int col = min(max((int)(p.x * 32.0f), 0), 31);
        int pixl = row * 32 + col;
        pixOf[ql] = pixl;
        atomicAdd(&cntS[pixl], 1);
    }
    __syncthreads();
    // exclusive scan of cntS[1024] with 256 threads (4 elems each)
    int a0 = cntS[4 * tid], a1 = cntS[4 * tid + 1], a2 = cntS[4 * tid + 2], a3 = cntS[4 * tid + 3];
    int tsum = a0 + a1 + a2 + a3;
    int lane = tid & 63, wv = tid >> 6;
    int v = tsum;
    for (int o = 1; o < 64; o <<= 1) { int u = __shfl_up(v, o); if (lane >= o) v += u; }
    if (lane == 63) wtot[wv] = v;
    __syncthreads();
    int wbase = 0;
    for (int w = 0; w < wv; ++w) wbase += wtot[w];
    int excl = wbase + v - tsum;
    preS[4 * tid] = excl;
    preS[4 * tid + 1] = excl + a0;
    preS[4 * tid + 2] = excl + a0 + a1;
    preS[4 * tid + 3] = excl + a0 + a1 + a2;
    __syncthreads();
    for (int i = tid; i < 1024; i += 256) offS[i] = preS[i];
    __syncthreads();
    for (int ql = tid; ql < 1024; ql += 256) {
        int p = pixOf[ql];
        int slot = atomicAdd(&offS[p], 1);
        qlist[base + slot] = base + ql;
    }
    for (int i = tid; i < 1024; i += 256) {
        qcnt[base + i] = cntS[i];
        qstart[base + i] = base + preS[i];
    }
}

// --------------------------- ball query (sample-resident, atomic-free) ------
__launch_bounds__(256)
__global__ void k_ballquery(const float* __restrict__ pos,
                            int* __restrict__ nbrs, int* __restrict__ nbr_cnt,
                            float* __restrict__ bqpart, float* __restrict__ defrep) {
    __shared__ float2 poss[1024];
    __shared__ float accd[1024], accx[1024], accy[1024];
    __shared__ unsigned long long cand[4][256];
    __shared__ int cnt[4], ocnt[4];
    int tid = threadIdx.x, wave = tid >> 6, lane = tid & 63;
    int s = blockIdx.x >> 4;           // sample
    int chunk = blockIdx.x & 15;       // 16 chunks of 64 queries
    int base = s << 10;
    for (int i = tid; i < 1024; i += 256) poss[i] = *(const float2*)&pos[2 * (base + i)];
    for (int i = tid; i < 1024; i += 256) { accd[i] = 0.0f; accx[i] = 0.0f; accy[i] = 0.0f; }
    __syncthreads();
    float2 pr[16];
#pragma unroll
    for (int k = 0; k < 16; ++k) pr[k] = poss[k * 64 + lane];

    float aD = 0, aE = 0, aF = 0;
    for (int qi = 0; qi < 16; ++qi) {
        int ql = chunk * 64 + wave * 16 + qi;
        int q = base + ql;
        float2 qp = poss[ql];
        int row = min(max((int)(qp.y * 32.0f), 0), 31);
        int col = min(max((int)(qp.x * 32.0f), 0), 31);
        int pixl = row * 32 + col;
        float2 tp = poss[pixl];
        if (lane == 0) { cnt[wave] = 0; ocnt[wave] = 0; }
        __builtin_amdgcn_wave_barrier();
#pragma unroll
        for (int k = 0; k < 16; ++k) {
            float dx = pr[k].x - qp.x, dy = pr[k].y - qp.y;
            float d2 = __fadd_rn(__fmul_rn(dx, dx), __fmul_rn(dy, dy)); // no FMA contraction
            if (d2 <= 0.01f) {
                int sl = atomicAdd(&cnt[wave], 1);
                if (sl < 256)
                    cand[wave][sl] = ((unsigned long long)__float_as_uint(d2) << 32)
                                     | (unsigned int)(k * 64 + lane);
            }
        }
        __builtin_amdgcn_wave_barrier();
        int c = min(cnt[wave], 256);
        for (int i = lane; i < c; i += 64) {
            unsigned long long key = cand[wave][i];
            int rank = 0;
            for (int t = 0; t < c; ++t) rank += (cand[wave][t] < key) ? 1 : 0;
            int j = (int)(key & 0xffffffffu);
            if (rank < KNB && j != pixl) {         // top-K, then remove_self_loops
                int sl = atomicAdd(&ocnt[wave], 1);
                nbrs[q * KNB + sl] = base + j;
                float rx = poss[j].x - tp.x, ry = poss[j].y - tp.y;
                aD += rx * rx; aE += rx * ry; aF += ry * ry;
                atomicAdd(&accd[j], 1.0f);
                atomicAdd(&accx[j], tp.x);
                atomicAdd(&accy[j], tp.y);
            }
        }
        __builtin_amdgcn_wave_barrier();
        if (lane == 0) nbr_cnt[q] = ocnt[wave];
    }
#pragma unroll
    for (int o = 1; o < 64; o <<= 1) {
        aD += __shfl_xor(aD, o); aE += __shfl_xor(aE, o); aF += __shfl_xor(aF, o);
    }
    __syncthreads();
    float* pb = &bqpart[blockIdx.x * 3072];
    for (int i = tid; i < 1024; i += 256) {
        pb[i] = accd[i]; pb[1024 + i] = accx[i]; pb[2048 + i] = accy[i];
    }
    if (tid == 0) {
        int r = (blockIdx.x & 63) * 4;
        atomicAdd(&defrep[r + 0], aD);
        atomicAdd(&defrep[r + 1], aE);
        atomicAdd(&defrep[r + 2], aF);
    }
}

// ------------------- sum the 16 chunk partials per node ---------------------
__global__ void k_nodeagg(const float* __restrict__ bqpart, float* __restrict__ deg,
                          float* __restrict__ stx, float* __restrict__ sty) {
    int t = blockIdx.x * 256 + threadIdx.x;   // 128 blocks -> 32768
    int s = t >> 10, off = t & 1023;
    const float* pb = &bqpart[(s * 16) * 3072];
    float d = 0, xx = 0, yy = 0;
    for (int j = 0; j < 16; ++j) {
        d  += pb[j * 3072 + off];
        xx += pb[j * 3072 + 1024 + off];
        yy += pb[j * 3072 + 2048 + off];
    }
    deg[t] = d; stx[t] = xx; sty[t] = yy;
}

// ---------------- node GEMM1 + folded BN node-stats: y = x@W1[:64]+b1 -------
// lane owns features f0=2*lane, f1=2*lane+1. yb packed (f0 lo, f1 hi).
__launch_bounds__(256)
__global__ void k_y(const float* __restrict__ x, const float* __restrict__ W1,
                    const float* __restrict__ b1, const float* __restrict__ pos,
                    const float* __restrict__ deg, const float* __restrict__ stxA,
                    const float* __restrict__ styA,
                    unsigned int* __restrict__ yb, float* __restrict__ partials) {
    __shared__ float w1s[64 * 128];
    __shared__ float stage[4][512];
    __shared__ float lsum[515];
    int tid = threadIdx.x;
    for (int i = tid; i < 64 * 128; i += 256) w1s[i] = W1[i];
    for (int i = tid; i < 515; i += 256) lsum[i] = 0.0f;
    __syncthreads();
    int wave = tid >> 6, lane = tid & 63;
    int f0 = 2 * lane, f1 = 2 * lane + 1;
    float b10 = b1[f0], b11 = b1[f1];
    float* st = &stage[wave][0];
    float P0 = 0, Q0 = 0, R0 = 0, S0 = 0, P1 = 0, Q1 = 0, R1 = 0, S1 = 0;
    float sB = 0, sC = 0, sDeg = 0;

    for (int it = 0; it < 4; ++it) {
        int nbase = ((blockIdx.x * 4 + wave) * 4 + it) * 8;
        __builtin_amdgcn_wave_barrier();
#pragma unroll
        for (int mm = 0; mm < 8; ++mm)
            st[mm * 64 + lane] = x[(nbase + mm) * 64 + lane];
        __builtin_amdgcn_wave_barrier();
        float z0[8], z1[8];
#pragma unroll
        for (int mm = 0; mm < 8; ++mm) { z0[mm] = b10; z1[mm] = b11; }
        for (int k4 = 0; k4 < 16; ++k4) {
            float2 wv0 = *(const float2*)&w1s[(k4 * 4 + 0) * 128 + f0];
            float2 wv1 = *(const float2*)&w1s[(k4 * 4 + 1) * 128 + f0];
            float2 wv2 = *(const float2*)&w1s[(k4 * 4 + 2) * 128 + f0];
            float2 wv3 = *(const float2*)&w1s[(k4 * 4 + 3) * 128 + f0];
#pragma unroll
            for (int mm = 0; mm < 8; ++mm) {
                float4 mk = *(const float4*)&st[mm * 64 + k4 * 4];
                z0[mm] += mk.x * wv0.x + mk.y * wv1.x + mk.z * wv2.x + mk.w * wv3.x;
                z1[mm] += mk.x * wv0.y + mk.y * wv1.y + mk.z * wv2.y + mk.w * wv3.y;
            }
        }
#pragma unroll
        for (int mm = 0; mm < 8; ++mm) {
            int n = nbase + mm;
            float dg = deg[n];
            float wgt = 1.0f + dg;
            float Bn = dg * pos[2 * n]     - stxA[n];
            float Cn = dg * pos[2 * n + 1] - styA[n];
            float a = z0[mm], bq = z1[mm];
            P0 += wgt * a;  Q0 += wgt * a * a;  R0 += a * Bn;  S0 += a * Cn;
            P1 += wgt * bq; Q1 += wgt * bq * bq; R1 += bq * Bn; S1 += bq * Cn;
            sB += Bn; sC += Cn; sDeg += dg;
            yb[n * 64 + lane] = pack_bf2(a, bq);
        }
    }
    atomicAdd(&lsum[f0], P0);        atomicAdd(&lsum[f1], P1);
    atomicAdd(&lsum[128 + f0], Q0);  atomicAdd(&lsum[128 + f1], Q1);
    atomicAdd(&lsum[256 + f0], R0);  atomicAdd(&lsum[256 + f1], R1);
    atomicAdd(&lsum[384 + f0], S0);  atomicAdd(&lsum[384 + f1], S1);
    if (lane == 0) {
        atomicAdd(&lsum[512], sB);
        atomicAdd(&lsum[513], sC);
        atomicAdd(&lsum[514], sDeg);
    }
    __syncthreads();
    for (int i = tid; i < 515; i += 256) partials[blockIdx.x * 516 + i] = lsum[i];
}

// --------------------------- finalize BN scale/shift ------------------------
__global__ void k_finalize(const float* __restrict__ gamma, const float* __restrict__ beta,
                           const float* __restrict__ W1, const float* __restrict__ partials,
                           const float* __restrict__ defrep, float* __restrict__ scsh) {
    __shared__ float red[515];
    __shared__ float sDEF[3];
    int tid = threadIdx.x;    // 256
    for (int i = tid; i < 515; i += 256) {
        float s = 0;
        for (int b = 0; b < 256; ++b) s += partials[b * 516 + i];
        red[i] = s;
    }
    if (tid < 3) {
        float s = 0;
        for (int r = 0; r < 64; ++r) s += defrep[r * 4 + tid];
        sDEF[tid] = s;
    }
    __syncthreads();
    if (tid < 128) {
        int f = tid;
        float P = red[f], Q = red[128 + f], R = red[256 + f], S = red[384 + f];
        float SB = red[512], SC = red[513], SDeg = red[514];
        float u = W1[8192 + f], v = W1[8320 + f];
        float cntv = 32768.0f + SDeg;
        float mean = (P + u * SB + v * SC) / cntv;
        float E2 = (Q + 2.0f * u * R + 2.0f * v * S
                    + u * u * sDEF[0] + 2.0f * u * v * sDEF[1] + v * v * sDEF[2]) / cntv;
        float var = E2 - mean * mean;
        float sc = gamma[f] / sqrtf(var + BN_EPS);
        scsh[f] = sc;
        scsh[128 + f] = beta[f] - mean * sc;
    }
}

// ---------- self pass (MFMA) + w precompute; stores only qcnt==0 nodes ------
__launch_bounds__(256)
__global__ void k_self(const unsigned int* __restrict__ yb, const float* __restrict__ pos,
                       const float* __restrict__ W1, const float* __restrict__ scsh,
                       const unsigned short* __restrict__ w2b, const float* __restrict__ b2,
                       const int* __restrict__ qcnt,
                       unsigned int* __restrict__ wbuf, float* __restrict__ out) {
    __shared__ unsigned short hbuf[4][16 * 136];   // 272 B row stride
    int tid = threadIdx.x, wave = tid >> 6, lane = tid & 63;
    unsigned short* hb = hbuf[wave];
    short8 bfrag[4][4];
#pragma unroll
    for (int t = 0; t < 4; ++t)
#pragma unroll
        for (int ks = 0; ks < 4; ++ks)
            bfrag[t][ks] = *(const short8*)&w2b[((t * 4 + ks) * 64 + lane) * 8];
    int f0 = 2 * lane;
    float sc0 = scsh[f0],     sh0 = scsh[128 + f0];
    float sc1 = scsh[f0 + 1], sh1 = scsh[129 + f0];
    float u0 = W1[8192 + f0], v0 = W1[8320 + f0];
    float u1 = W1[8193 + f0], v1 = W1[8321 + f0];
    float b2v0 = b2[(lane & 15)],      b2v1 = b2[16 + (lane & 15)];
    float b2v2 = b2[32 + (lane & 15)], b2v3 = b2[48 + (lane & 15)];

    int nbase = (blockIdx.x * 4 + wave) * 16;
#pragma unroll
    for (int c = 0; c < 2; ++c) {
        unsigned int yw[8];
#pragma unroll
        for (int j = 0; j < 8; ++j)
            yw[j] = yb[(nbase + c * 8 + j) * 64 + lane];
#pragma unroll
        for (int j = 0; j < 8; ++j) {
            int e = c * 8 + j;
            int nn = nbase + e;
            float y0 = bf_lo(yw[j]), y1 = bf_hi(yw[j]);
            float h0 = fmaxf(y0 * sc0 + sh0, 0.0f);
            float h1 = fmaxf(y1 * sc1 + sh1, 0.0f);
            *(unsigned int*)&hb[e * 136 + f0] = pack_bf2(h0, h1);
            float px = pos[2 * nn], py = pos[2 * nn + 1];
            float w0 = (y0 + px * u0 + py * v0) * sc0;
            float w1 = (y1 + px * u1 + py * v1) * sc1;
            wbuf[nn * 64 + lane] = pack_bf2(w0, w1);
        }
    }
    __builtin_amdgcn_wave_barrier();
    floatx4 acc0 = {0,0,0,0}, acc1 = {0,0,0,0}, acc2 = {0,0,0,0}, acc3 = {0,0,0,0};
#pragma unroll
    for (int ks = 0; ks < 4; ++ks) {
        short8 a = *(const short8*)&hb[(lane & 15) * 136 + ks * 32 + (lane >> 4) * 8];
        acc0 = __builtin_amdgcn_mfma_f32_16x16x32_bf16(a, bfrag[0][ks], acc0, 0, 0, 0);
        acc1 = __builtin_amdgcn_mfma_f32_16x16x32_bf16(a, bfrag[1][ks], acc1, 0, 0, 0);
        acc2 = __builtin_amdgcn_mfma_f32_16x16x32_bf16(a, bfrag[2][ks], acc2, 0, 0, 0);
        acc3 = __builtin_amdgcn_mfma_f32_16x16x32_bf16(a, bfrag[3][ks], acc3, 0, 0, 0);
    }
    int nrow = nbase + (lane >> 4) * 4;
#pragma unroll
    for (int r = 0; r < 4; ++r) {
        int n = nrow + r;
        if (qcnt[n] == 0) {                    // pixels with queries are owned by k_out
            int obase = (n >> 10) * 65536 + (n & 1023);
            out[obase + ((lane & 15)) * 1024]      = acc0[r] + b2v0;
            out[obase + (16 + (lane & 15)) * 1024] = acc1[r] + b2v1;
            out[obase + (32 + (lane & 15)) * 1024] = acc2[r] + b2v2;
            out[obase + (48 + (lane & 15)) * 1024] = acc3[r] + b2v3;
        }
    }
}

// ---------- neighbor pass: wave per pixel, stream edges, plain store --------
__launch_bounds__(256)
__global__ void k_out(const unsigned int* __restrict__ wbuf, const float* __restrict__ pos,
                      const float* __restrict__ W1, const float* __restrict__ scsh,
                      const unsigned short* __restrict__ w2b, const float* __restrict__ b2,
                      const int* __restrict__ nbrs, const int* __restrict__ nbr_cnt,
                      const int* __restrict__ qcnt, const int* __restrict__ qstart,
                      const int* __restrict__ qlist, float* __restrict__ out) {
    __shared__ unsigned short hbuf[4][16 * 136];
    int tid = threadIdx.x, wave = tid >> 6, lane = tid & 63;
    int n = blockIdx.x * 4 + wave;         // pixel node
    int c = qcnt[n];
    if (c == 0) return;                    // k_self wrote this node
    unsigned short* hb = hbuf[wave];
    short8 bfrag[4][4];
#pragma unroll
    for (int t = 0; t < 4; ++t)
#pragma unroll
        for (int ks = 0; ks < 4; ++ks)
            bfrag[t][ks] = *(const short8*)&w2b[((t * 4 + ks) * 64 + lane) * 8];
    int f0 = 2 * lane;
    float sc0 = scsh[f0],     sh0 = scsh[128 + f0];
    float sc1 = scsh[f0 + 1], sh1 = scsh[129 + f0];
    float u0 = W1[8192 + f0], v0 = W1[8320 + f0];
    float u1 = W1[8193 + f0], v1 = W1[8321 + f0];
    float b2l = b2[lane];
    int b = n >> 10, pixl = n & 1023;
    float tx = pos[2 * n], ty = pos[2 * n + 1];
    float shp0 = sh0 - (tx * u0 + ty * v0) * sc0;
    float shp1 = sh1 - (tx * u1 + ty * v1) * sc1;
    int qs = qstart[n];

    float om0[4], om1[4], om2[4], om3[4];
#pragma unroll
    for (int r = 0; r < 4; ++r) { om0[r] = -INFINITY; om1[r] = -INFINITY; om2[r] = -INFINITY; om3[r] = -INFINITY; }

    auto flush = [&](int nvalid) {
        __builtin_amdgcn_wave_barrier();
        floatx4 a0 = {0,0,0,0}, a1 = {0,0,0,0}, a2 = {0,0,0,0}, a3 = {0,0,0,0};
#pragma unroll
        for (int ks = 0; ks < 4; ++ks) {
            short8 a = *(const short8*)&hb[(lane & 15) * 136 + ks * 32 + (lane >> 4) * 8];
            a0 = __builtin_amdgcn_mfma_f32_16x16x32_bf16(a, bfrag[0][ks], a0, 0, 0, 0);
            a1 = __builtin_amdgcn_mfma_f32_16x16x32_bf16(a, bfrag[1][ks], a1, 0, 0, 0);
            a2 = __builtin_amdgcn_mfma_f32_16x16x32_bf16(a, bfrag[2][ks], a2, 0, 0, 0);
            a3 = __builtin_amdgcn_mfma_f32_16x16x32_bf16(a, bfrag[3][ks], a3, 0, 0, 0);
        }
        __builtin_amdgcn_wave_barrier();
        int rowb = (lane >> 4) * 4;
#pragma unroll
        for (int r = 0; r < 4; ++r) {
            if (rowb + r < nvalid) {
                om0[r] = fmaxf(om0[r], a0[r]);
                om1[r] = fmaxf(om1[r], a1[r]);
                om2[r] = fmaxf(om2[r], a2[r]);
                om3[r] = fmaxf(om3[r], a3[r]);
            }
        }
    };

    int fill = 0;
    {   // self message: src = n (t-terms cancel exactly: w[n]+shp = y*sc+sh)
        unsigned int yw = wbuf[n * 64 + lane];
        float h0 = fmaxf(bf_lo(yw) + shp0, 0.0f);
        float h1 = fmaxf(bf_hi(yw) + shp1, 0.0f);
        *(unsigned int*)&hb[fill * 136 + f0] = pack_bf2(h0, h1);
        fill = 1;
    }
    for (int i = 0; i < c; ++i) {
        int q = qlist[qs + i];
        int m = nbr_cnt[q];
        int nv = (lane < m) ? nbrs[q * KNB + lane] : 0;
        for (int base = 0; base < m; base += 8) {
            int g = min(8, m - base);
            unsigned int yw[8];
#pragma unroll
            for (int j = 0; j < 8; ++j) {
                if (j < g) {
                    int src = __shfl(nv, base + j);
                    yw[j] = wbuf[src * 64 + lane];
                }
            }
#pragma unroll
            for (int j = 0; j < 8; ++j) {
                if (j < g) {
                    float h0 = fmaxf(bf_lo(yw[j]) + shp0, 0.0f);
                    float h1 = fmaxf(bf_hi(yw[j]) + shp1, 0.0f);
                    *(unsigned int*)&hb[fill * 136 + f0] = pack_bf2(h0, h1);
                    ++fill;
                    if (fill == 16) { flush(16); fill = 0; }
                }
            }
        }
    }
    if (fill > 0) flush(fill);

    float w0 = fmaxf(fmaxf(om0[0], om0[1]), fmaxf(om0[2], om0[3]));
    float w1 = fmaxf(fmaxf(om1[0], om1[1]), fmaxf(om1[2], om1[3]));
    float w2 = fmaxf(fmaxf(om2[0], om2[1]), fmaxf(om2[2], om2[3]));
    float w3 = fmaxf(fmaxf(om3[0], om3[1]), fmaxf(om3[2], om3[3]));
    w0 = fmaxf(w0, __shfl_xor(w0, 16)); w0 = fmaxf(w0, __shfl_xor(w0, 32));
    w1 = fmaxf(w1, __shfl_xor(w1, 16)); w1 = fmaxf(w1, __shfl_xor(w1, 32));
    w2 = fmaxf(w2, __shfl_xor(w2, 16)); w2 = fmaxf(w2, __shfl_xor(w2, 32));
    w3 = fmaxf(w3, __shfl_xor(w3, 16)); w3 = fmaxf(w3, __shfl_xor(w3, 32));
    int g = lane >> 4;   // feature = g*16 + (lane&15) = lane
    float vf = (g == 0) ? w0 : (g == 1) ? w1 : (g == 2) ? w2 : w3;
    vf += b2l;
    out[b * 65536 + lane * 1024 + pixl] = vf;   // single plain store, no atomics
}

extern "C" void kernel_launch(void* const* d_in, const int* in_sizes, int n_in,
                              void* d_out, int out_size, void* d_ws, size_t ws_size,
                              hipStream_t stream) {
    const float* x     = (const float*)d_in[0];
    const float* pos   = (const float*)d_in[1];
    // d_in[2] = batch (unused: points are sorted, b = idx >> 10)
    const float* W1    = (const float*)d_in[3];
    const float* b1    = (const float*)d_in[4];
    const float* gamma = (const float*)d_in[5];
    const float* beta  = (const float*)d_in[6];
    const float* W2    = (const float*)d_in[7];
    const float* b2    = (const float*)d_in[8];
    float* out = (float*)d_out;
    char* ws = (char*)d_ws;
    int*   nbrs     = (int*)(ws + WS_NBRS);
    int*   nbr_cnt  = (int*)(ws + WS_NBRCNT);
    float* deg      = (float*)(ws + WS_DEG);
    float* stx      = (float*)(ws + WS_STX);
    float* sty      = (float*)(ws + WS_STY);
    float* defrep   = (float*)(ws + WS_DEFREP);
    float* scsh     = (float*)(ws + WS_SCSH);
    unsigned short* w2b = (unsigned short*)(ws + WS_W2B);
    float* partials = (float*)(ws + WS_PART);
    unsigned int* yb = (unsigned int*)(ws + WS_Y);
    float* bqpart   = (float*)(ws + WS_BQPART);
    unsigned int* wbuf = (unsigned int*)(ws + WS_WB);   // overlays bqpart (dead after k_nodeagg)
    int* qcnt   = (int*)(ws + WS_QCNT);
    int* qstart = (int*)(ws + WS_QSTART);
    int* qlist  = (int*)(ws + WS_QLIST);

    k_prep<<<32, 256, 0, stream>>>(W2, w2b, defrep);
    k_pixmap<<<32, 256, 0, stream>>>(pos, qcnt, qstart, qlist);
    k_ballquery<<<512, 256, 0, stream>>>(pos, nbrs, nbr_cnt, bqpart, defrep);
    k_nodeagg<<<128, 256, 0, stream>>>(bqpart, deg, stx, sty);
    k_y<<<256, 256, 0, stream>>>(x, W1, b1, pos, deg, stx, sty, yb, partials);
    k_finalize<<<1, 256, 0, stream>>>(gamma, beta, W1, partials, defrep, scsh);
    k_self<<<NPTS / 64, 256, 0, stream>>>(yb, pos, W1, scsh, w2b, b2, qcnt, wbuf, out);
    k_out<<<NPTS / 4, 256, 0, stream>>>(wbuf, pos, W1, scsh, w2b, b2,
                                        nbrs, nbr_cnt, qcnt, qstart, qlist, out);
}

// Round 7
// 298.946 us; speedup vs baseline: 1.3463x; 1.3463x over previous
//
#include <hip/hip_runtime.h>
#include <hip/hip_bf16.h>
#include <math.h>

// ---------------------------------------------------------------------------
// PointsToImage: ball-query (K=32, R=0.1) -> PointNetConv msg=[x_j, pos_j-pos_dst]
// -> Linear(66,128) -> masked-BatchNorm -> ReLU -> Linear(128,64) -> scatter-max
// into pixel nodes, output [B=32, F=64, 32, 32] fp32.
//
// R7: R6's pixel-owned k_out was load-imbalanced (Poisson tail, 37% idle waves,
// VALUBusy 21%). Revert to UNIFORM query-owned k_out (2 queries/wave, m<=32)
// keeping R6's hoisted edge math h=relu(w[src]+shp(q)); replace output atomics
// with plain stores into pixel-sorted scratch slots (islot = inverse qlist
// permutation), then a tiny uniform k_gather maxes each pixel's contiguous
// slots against the node's self result (selfbuf, coalesced) and stores out.
// Pipeline: k_prep -> k_pixmap -> k_ballquery -> k_nodeagg -> k_y -> k_finalize
//           -> k_self -> k_out -> k_gather
// ---------------------------------------------------------------------------

#define NPTS   32768
#define KNB    32
#define BN_EPS 1e-5f

// workspace layout (bytes)
#define WS_NBRS     0u           // int[NPTS*KNB]      = 4194304
#define WS_NBRCNT   4194304u     // int[NPTS]          = 131072
#define WS_DEG      4325376u     // float[NPTS]        = 131072
#define WS_STX      4456448u     // float[NPTS]        = 131072
#define WS_STY      4587520u     // float[NPTS]        = 131072
#define WS_DEFREP   4718592u     // float[64*4]        = 1024
#define WS_SCSH     4719616u     // float[256]         = 1024
#define WS_W2B      4720640u     // ushort[8192]       = 16384
#define WS_PART     4737024u     // float[256*516]     = 528384
#define WS_Y        5265408u     // uint[NPTS*64]      = 8388608 (yb; dead after k_self)
#define WS_SCRATCH  5265408u     // float[NPTS*64]     = 8388608 (per-query maxima; OVERLAYS yb)
#define WS_BQPART   13654016u    // float[512*3072]    = 6291456 (consumed by k_nodeagg)
#define WS_WB       13654016u    // uint[NPTS*64]      = 8388608 (w, bf16; OVERLAYS bqpart)
#define WS_QCNT     22042624u    // int[NPTS]          = 131072
#define WS_QSTART   22173696u    // int[NPTS]          = 131072
#define WS_QLIST    22304768u    // int[NPTS]          = 131072
#define WS_ISLOT    22435840u    // int[NPTS]          = 131072
#define WS_SELF     22566912u    // float[NPTS*64]     = 8388608 (self-msg MLP out, contiguous)

typedef __attribute__((ext_vector_type(8))) short short8;
typedef __attribute__((ext_vector_type(4))) float floatx4;

__device__ __forceinline__ unsigned short f2bf(float f) {
    unsigned int u = __float_as_uint(f);
    unsigned int r = u + 0x7fffu + ((u >> 16) & 1u);   // RNE
    return (unsigned short)(r >> 16);
}
__device__ __forceinline__ float bf_lo(unsigned int w) { return __uint_as_float(w << 16); }
__device__ __forceinline__ float bf_hi(unsigned int w) { return __uint_as_float(w & 0xffff0000u); }
__device__ __forceinline__ unsigned int pack_bf2(float lo, float hi) {
    __hip_bfloat162 hh = __float22bfloat162_rn(make_float2(lo, hi));
    return *reinterpret_cast<unsigned int*>(&hh);
}

// ------------------- prep: zero defrep, pack W2 into B-frag bf16 ------------
__global__ void k_prep(const float* __restrict__ W2, unsigned short* __restrict__ w2b,
                       float* __restrict__ defrep) {
    int t = blockIdx.x * 256 + threadIdx.x;     // 32 blocks * 256 = 8192
    if (t < 256) defrep[t] = 0.0f;
    if (t < 8192) {
        int j  = t & 7;
        int L  = (t >> 3) & 63;
        int ks = (t >> 9) & 3;
        int t4 = t >> 11;
        int k = ks * 32 + (L >> 4) * 8 + j;
        int n = t4 * 16 + (L & 15);
        w2b[t] = f2bf(W2[k * 64 + n]);
    }
}

// ------------------- pixel map: invert query -> pixel (per sample) ----------
__launch_bounds__(256)
__global__ void k_pixmap(const float* __restrict__ pos, int* __restrict__ qcnt,
                         int* __restrict__ qstart, int* __restrict__ qlist,
                         int* __restrict__ islot) {
    __shared__ int cntS[1024], preS[1024], offS[1024], pixOf[1024];
    __shared__ int wtot[4];
    int tid = threadIdx.x;
    int s = blockIdx.x;
    int base = s << 10;
    for (int i = tid; i < 1024; i += 256) cntS[i] = 0;
    __syncthreads();
    for (int ql = tid; ql < 1024; ql += 256) {
        float2 p = *(const float2*)&pos[2 * (base + ql)];
        int row = min(max((int)(p.y * 32.0f), 0), 31);
        int col = min(max((int)(p.x * 32.0f), 0), 31);
        int pixl = row * 32 + col;
        pixOf[ql] = pixl;
        atomicAdd(&cntS[pixl], 1);
    }
    __syncthreads();
    // exclusive scan of cntS[1024] with 256 threads (4 elems each)
    int a0 = cntS[4 * tid], a1 = cntS[4 * tid + 1], a2 = cntS[4 * tid + 2], a3 = cntS[4 * tid + 3];
    int tsum = a0 + a1 + a2 + a3;
    int lane = tid & 63, wv = tid >> 6;
    int v = tsum;
    for (int o = 1; o < 64; o <<= 1) { int u = __shfl_up(v, o); if (lane >= o) v += u; }
    if (lane == 63) wtot[wv] = v;
    __syncthreads();
    int wbase = 0;
    for (int w = 0; w < wv; ++w) wbase += wtot[w];
    int excl = wbase + v - tsum;
    preS[4 * tid] = excl;
    preS[4 * tid + 1] = excl + a0;
    preS[4 * tid + 2] = excl + a0 + a1;
    preS[4 * tid + 3] = excl + a0 + a1 + a2;
    __syncthreads();
    for (int i = tid; i < 1024; i += 256) offS[i] = preS[i];
    __syncthreads();
    for (int ql = tid; ql < 1024; ql += 256) {
        int p = pixOf[ql];
        int slot = atomicAdd(&offS[p], 1);
        qlist[base + slot] = base + ql;
        islot[base + ql] = base + slot;
    }
    for (int i = tid; i < 1024; i += 256) {
        qcnt[base + i] = cntS[i];
        qstart[base + i] = base + preS[i];
    }
}

// --------------------------- ball query (sample-resident, atomic-free) ------
__launch_bounds__(256)
__global__ void k_ballquery(const float* __restrict__ pos,
                            int* __restrict__ nbrs, int* __restrict__ nbr_cnt,
                            float* __restrict__ bqpart, float* __restrict__ defrep) {
    __shared__ float2 poss[1024];
    __shared__ float accd[1024], accx[1024], accy[1024];
    __shared__ unsigned long long cand[4][256];
    __shared__ int cnt[4], ocnt[4];
    int tid = threadIdx.x, wave = tid >> 6, lane = tid & 63;
    int s = blockIdx.x >> 4;           // sample
    int chunk = blockIdx.x & 15;       // 16 chunks of 64 queries
    int base = s << 10;
    for (int i = tid; i < 1024; i += 256) poss[i] = *(const float2*)&pos[2 * (base + i)];
    for (int i = tid; i < 1024; i += 256) { accd[i] = 0.0f; accx[i] = 0.0f; accy[i] = 0.0f; }
    __syncthreads();
    float2 pr[16];
#pragma unroll
    for (int k = 0; k < 16; ++k) pr[k] = poss[k * 64 + lane];

    float aD = 0, aE = 0, aF = 0;
    for (int qi = 0; qi < 16; ++qi) {
        int ql = chunk * 64 + wave * 16 + qi;
        int q = base + ql;
        float2 qp = poss[ql];
        int row = min(max((int)(qp.y * 32.0f), 0), 31);
        int col = min(max((int)(qp.x * 32.0f), 0), 31);
        int pixl = row * 32 + col;
        float2 tp = poss[pixl];
        if (lane == 0) { cnt[wave] = 0; ocnt[wave] = 0; }
        __builtin_amdgcn_wave_barrier();
#pragma unroll
        for (int k = 0; k < 16; ++k) {
            float dx = pr[k].x - qp.x, dy = pr[k].y - qp.y;
            float d2 = __fadd_rn(__fmul_rn(dx, dx), __fmul_rn(dy, dy)); // no FMA contraction
            if (d2 <= 0.01f) {
                int sl = atomicAdd(&cnt[wave], 1);
                if (sl < 256)
                    cand[wave][sl] = ((unsigned long long)__float_as_uint(d2) << 32)
                                     | (unsigned int)(k * 64 + lane);
            }
        }
        __builtin_amdgcn_wave_barrier();
        int c = min(cnt[wave], 256);
        for (int i = lane; i < c; i += 64) {
            unsigned long long key = cand[wave][i];
            int rank = 0;
            for (int t = 0; t < c; ++t) rank += (cand[wave][t] < key) ? 1 : 0;
            int j = (int)(key & 0xffffffffu);
            if (rank < KNB && j != pixl) {         // top-K, then remove_self_loops
                int sl = atomicAdd(&ocnt[wave], 1);
                nbrs[q * KNB + sl] = base + j;
                float rx = poss[j].x - tp.x, ry = poss[j].y - tp.y;
                aD += rx * rx; aE += rx * ry; aF += ry * ry;
                atomicAdd(&accd[j], 1.0f);
                atomicAdd(&accx[j], tp.x);
                atomicAdd(&accy[j], tp.y);
            }
        }
        __builtin_amdgcn_wave_barrier();
        if (lane == 0) nbr_cnt[q] = ocnt[wave];
    }
#pragma unroll
    for (int o = 1; o < 64; o <<= 1) {
        aD += __shfl_xor(aD, o); aE += __shfl_xor(aE, o); aF += __shfl_xor(aF, o);
    }
    __syncthreads();
    float* pb = &bqpart[blockIdx.x * 3072];
    for (int i = tid; i < 1024; i += 256) {
        pb[i] = accd[i]; pb[1024 + i] = accx[i]; pb[2048 + i] = accy[i];
    }
    if (tid == 0) {
        int r = (blockIdx.x & 63) * 4;
        atomicAdd(&defrep[r + 0], aD);
        atomicAdd(&defrep[r + 1], aE);
        atomicAdd(&defrep[r + 2], aF);
    }
}

// ------------------- sum the 16 chunk partials per node ---------------------
__global__ void k_nodeagg(const float* __restrict__ bqpart, float* __restrict__ deg,
                          float* __restrict__ stx, float* __restrict__ sty) {
    int t = blockIdx.x * 256 + threadIdx.x;   // 128 blocks -> 32768
    int s = t >> 10, off = t & 1023;
    const float* pb = &bqpart[(s * 16) * 3072];
    float d = 0, xx = 0, yy = 0;
    for (int j = 0; j < 16; ++j) {
        d  += pb[j * 3072 + off];
        xx += pb[j * 3072 + 1024 + off];
        yy += pb[j * 3072 + 2048 + off];
    }
    deg[t] = d; stx[t] = xx; sty[t] = yy;
}

// ---------------- node GEMM1 + folded BN node-stats: y = x@W1[:64]+b1 -------
// lane owns features f0=2*lane, f1=2*lane+1. yb packed (f0 lo, f1 hi).
__launch_bounds__(256)
__global__ void k_y(const float* __restrict__ x, const float* __restrict__ W1,
                    const float* __restrict__ b1, const float* __restrict__ pos,
                    const float* __restrict__ deg, const float* __restrict__ stxA,
                    const float* __restrict__ styA,
                    unsigned int* __restrict__ yb, float* __restrict__ partials) {
    __shared__ float w1s[64 * 128];
    __shared__ float stage[4][512];
    __shared__ float lsum[515];
    int tid = threadIdx.x;
    for (int i = tid; i < 64 * 128; i += 256) w1s[i] = W1[i];
    for (int i = tid; i < 515; i += 256) lsum[i] = 0.0f;
    __syncthreads();
    int wave = tid >> 6, lane = tid & 63;
    int f0 = 2 * lane, f1 = 2 * lane + 1;
    float b10 = b1[f0], b11 = b1[f1];
    float* st = &stage[wave][0];
    float P0 = 0, Q0 = 0, R0 = 0, S0 = 0, P1 = 0, Q1 = 0, R1 = 0, S1 = 0;
    float sB = 0, sC = 0, sDeg = 0;

    for (int it = 0; it < 4; ++it) {
        int nbase = ((blockIdx.x * 4 + wave) * 4 + it) * 8;
        __builtin_amdgcn_wave_barrier();
#pragma unroll
        for (int mm = 0; mm < 8; ++mm)
            st[mm * 64 + lane] = x[(nbase + mm) * 64 + lane];
        __builtin_amdgcn_wave_barrier();
        float z0[8], z1[8];
#pragma unroll
        for (int mm = 0; mm < 8; ++mm) { z0[mm] = b10; z1[mm] = b11; }
        for (int k4 = 0; k4 < 16; ++k4) {
            float2 wv0 = *(const float2*)&w1s[(k4 * 4 + 0) * 128 + f0];
            float2 wv1 = *(const float2*)&w1s[(k4 * 4 + 1) * 128 + f0];
            float2 wv2 = *(const float2*)&w1s[(k4 * 4 + 2) * 128 + f0];
            float2 wv3 = *(const float2*)&w1s[(k4 * 4 + 3) * 128 + f0];
#pragma unroll
            for (int mm = 0; mm < 8; ++mm) {
                float4 mk = *(const float4*)&st[mm * 64 + k4 * 4];
                z0[mm] += mk.x * wv0.x + mk.y * wv1.x + mk.z * wv2.x + mk.w * wv3.x;
                z1[mm] += mk.x * wv0.y + mk.y * wv1.y + mk.z * wv2.y + mk.w * wv3.y;
            }
        }
#pragma unroll
        for (int mm = 0; mm < 8; ++mm) {
            int n = nbase + mm;
            float dg = deg[n];
            float wgt = 1.0f + dg;
            float Bn = dg * pos[2 * n]     - stxA[n];
            float Cn = dg * pos[2 * n + 1] - styA[n];
            float a = z0[mm], bq = z1[mm];
            P0 += wgt * a;  Q0 += wgt * a * a;  R0 += a * Bn;  S0 += a * Cn;
            P1 += wgt * bq; Q1 += wgt * bq * bq; R1 += bq * Bn; S1 += bq * Cn;
            sB += Bn; sC += Cn; sDeg += dg;
            yb[n * 64 + lane] = pack_bf2(a, bq);
        }
    }
    atomicAdd(&lsum[f0], P0);        atomicAdd(&lsum[f1], P1);
    atomicAdd(&lsum[128 + f0], Q0);  atomicAdd(&lsum[128 + f1], Q1);
    atomicAdd(&lsum[256 + f0], R0);  atomicAdd(&lsum[256 + f1], R1);
    atomicAdd(&lsum[384 + f0], S0);  atomicAdd(&lsum[384 + f1], S1);
    if (lane == 0) {
        atomicAdd(&lsum[512], sB);
        atomicAdd(&lsum[513], sC);
        atomicAdd(&lsum[514], sDeg);
    }
    __syncthreads();
    for (int i = tid; i < 515; i += 256) partials[blockIdx.x * 516 + i] = lsum[i];
}

// --------------------------- finalize BN scale/shift ------------------------
__global__ void k_finalize(const float* __restrict__ gamma, const float* __restrict__ beta,
                           const float* __restrict__ W1, const float* __restrict__ partials,
                           const float* __restrict__ defrep, float* __restrict__ scsh) {
    __shared__ float red[515];
    __shared__ float sDEF[3];
    int tid = threadIdx.x;    // 256
    for (int i = tid; i < 515; i += 256) {
        float s = 0;
        for (int b = 0; b < 256; ++b) s += partials[b * 516 + i];
        red[i] = s;
    }
    if (tid < 3) {
        float s = 0;
        for (int r = 0; r < 64; ++r) s += defrep[r * 4 + tid];
        sDEF[tid] = s;
    }
    __syncthreads();
    if (tid < 128) {
        int f = tid;
        float P = red[f], Q = red[128 + f], R = red[256 + f], S = red[384 + f];
        float SB = red[512], SC = red[513], SDeg = red[514];
        float u = W1[8192 + f], v = W1[8320 + f];
        float cntv = 32768.0f + SDeg;
        float mean = (P + u * SB + v * SC) / cntv;
        float E2 = (Q + 2.0f * u * R + 2.0f * v * S
                    + u * u * sDEF[0] + 2.0f * u * v * sDEF[1] + v * v * sDEF[2]) / cntv;
        float var = E2 - mean * mean;
        float sc = gamma[f] / sqrtf(var + BN_EPS);
        scsh[f] = sc;
        scsh[128 + f] = beta[f] - mean * sc;
    }
}

// ---------- self pass (MFMA) + w precompute; writes out + selfbuf -----------
__launch_bounds__(256)
__global__ void k_self(const unsigned int* __restrict__ yb, const float* __restrict__ pos,
                       const float* __restrict__ W1, const float* __restrict__ scsh,
                       const unsigned short* __restrict__ w2b, const float* __restrict__ b2,
                       unsigned int* __restrict__ wbuf, float* __restrict__ selfbuf,
                       float* __restrict__ out) {
    __shared__ unsigned short hbuf[4][16 * 136];   // 272 B row stride
    int tid = threadIdx.x, wave = tid >> 6, lane = tid & 63;
    unsigned short* hb = hbuf[wave];
    short8 bfrag[4][4];
#pragma unroll
    for (int t = 0; t < 4; ++t)
#pragma unroll
        for (int ks = 0; ks < 4; ++ks)
            bfrag[t][ks] = *(const short8*)&w2b[((t * 4 + ks) * 64 + lane) * 8];
    int f0 = 2 * lane;
    float sc0 = scsh[f0],     sh0 = scsh[128 + f0];
    float sc1 = scsh[f0 + 1], sh1 = scsh[129 + f0];
    float u0 = W1[8192 + f0], v0 = W1[8320 + f0];
    float u1 = W1[8193 + f0], v1 = W1[8321 + f0];
    float b2v0 = b2[(lane & 15)],      b2v1 = b2[16 + (lane & 15)];
    float b2v2 = b2[32 + (lane & 15)], b2v3 = b2[48 + (lane & 15)];

    int nbase = (blockIdx.x * 4 + wave) * 16;
#pragma unroll
    for (int c = 0; c < 2; ++c) {
        unsigned int yw[8];
#pragma unroll
        for (int j = 0; j < 8; ++j)
            yw[j] = yb[(nbase + c * 8 + j) * 64 + lane];
#pragma unroll
        for (int j = 0; j < 8; ++j) {
            int e = c * 8 + j;
            int nn = nbase + e;
            float y0 = bf_lo(yw[j]), y1 = bf_hi(yw[j]);
            float h0 = fmaxf(y0 * sc0 + sh0, 0.0f);
            float h1 = fmaxf(y1 * sc1 + sh1, 0.0f);
            *(unsigned int*)&hb[e * 136 + f0] = pack_bf2(h0, h1);
            float px = pos[2 * nn], py = pos[2 * nn + 1];
            float w0 = (y0 + px * u0 + py * v0) * sc0;
            float w1 = (y1 + px * u1 + py * v1) * sc1;
            wbuf[nn * 64 + lane] = pack_bf2(w0, w1);
        }
    }
    __builtin_amdgcn_wave_barrier();
    floatx4 acc0 = {0,0,0,0}, acc1 = {0,0,0,0}, acc2 = {0,0,0,0}, acc3 = {0,0,0,0};
#pragma unroll
    for (int ks = 0; ks < 4; ++ks) {
        short8 a = *(const short8*)&hb[(lane & 15) * 136 + ks * 32 + (lane >> 4) * 8];
        acc0 = __builtin_amdgcn_mfma_f32_16x16x32_bf16(a, bfrag[0][ks], acc0, 0, 0, 0);
        acc1 = __builtin_amdgcn_mfma_f32_16x16x32_bf16(a, bfrag[1][ks], acc1, 0, 0, 0);
        acc2 = __builtin_amdgcn_mfma_f32_16x16x32_bf16(a, bfrag[2][ks], acc2, 0, 0, 0);
        acc3 = __builtin_amdgcn_mfma_f32_16x16x32_bf16(a, bfrag[3][ks], acc3, 0, 0, 0);
    }
    int nrow = nbase + (lane >> 4) * 4;
#pragma unroll
    for (int r = 0; r < 4; ++r) {
        int n = nrow + r;
        int obase = (n >> 10) * 65536 + (n & 1023);
        float o0 = acc0[r] + b2v0, o1 = acc1[r] + b2v1;
        float o2 = acc2[r] + b2v2, o3 = acc3[r] + b2v3;
        out[obase + ((lane & 15)) * 1024]      = o0;
        out[obase + (16 + (lane & 15)) * 1024] = o1;
        out[obase + (32 + (lane & 15)) * 1024] = o2;
        out[obase + (48 + (lane & 15)) * 1024] = o3;
        selfbuf[n * 64 + (lane & 15)]      = o0;   // contiguous copy for k_gather
        selfbuf[n * 64 + 16 + (lane & 15)] = o1;
        selfbuf[n * 64 + 32 + (lane & 15)] = o2;
        selfbuf[n * 64 + 48 + (lane & 15)] = o3;
    }
}

// ---------- neighbor pass: query-owned, uniform; store to sorted scratch ----
__launch_bounds__(256)
__global__ void k_out(const unsigned int* __restrict__ wbuf, const float* __restrict__ pos,
                      const float* __restrict__ W1, const float* __restrict__ scsh,
                      const unsigned short* __restrict__ w2b, const float* __restrict__ b2,
                      const int* __restrict__ nbrs, const int* __restrict__ nbr_cnt,
                      const int* __restrict__ islot, float* __restrict__ scratch) {
    __shared__ unsigned short hbuf[4][16 * 136];
    int tid = threadIdx.x, wave = tid >> 6, lane = tid & 63;
    unsigned short* hb = hbuf[wave];
    short8 bfrag[4][4];
#pragma unroll
    for (int t = 0; t < 4; ++t)
#pragma unroll
        for (int ks = 0; ks < 4; ++ks)
            bfrag[t][ks] = *(const short8*)&w2b[((t * 4 + ks) * 64 + lane) * 8];
    int f0 = 2 * lane;
    float sc0 = scsh[f0],     sh0 = scsh[128 + f0];
    float sc1 = scsh[f0 + 1], sh1 = scsh[129 + f0];
    float u0 = W1[8192 + f0], v0 = W1[8320 + f0];
    float u1 = W1[8193 + f0], v1 = W1[8321 + f0];
    float b2l = b2[lane];
    int wid = blockIdx.x * 4 + wave;     // 16384 waves, 2 queries each

    for (int qi = 0; qi < 2; ++qi) {
        int q = wid * 2 + qi;
        int m = nbr_cnt[q];              // m <= 32 always
        int b = q >> 10;
        float qx = pos[2 * q], qy = pos[2 * q + 1];
        int row = min(max((int)(qy * 32.0f), 0), 31);
        int col = min(max((int)(qx * 32.0f), 0), 31);
        int pixq = (b << 10) + row * 32 + col;
        float tx = pos[2 * pixq], ty = pos[2 * pixq + 1];
        float shp0 = sh0 - (tx * u0 + ty * v0) * sc0;
        float shp1 = sh1 - (tx * u1 + ty * v1) * sc1;
        int nv = (lane < m) ? nbrs[q * KNB + lane] : 0;
        float om0[4], om1[4], om2[4], om3[4];
#pragma unroll
        for (int r = 0; r < 4; ++r) { om0[r] = -INFINITY; om1[r] = -INFINITY; om2[r] = -INFINITY; om3[r] = -INFINITY; }

        for (int mt = 0; mt * 16 < m; ++mt) {       // at most 2 tiles
            int g = min(16, m - mt * 16);
#pragma unroll
            for (int c = 0; c < 2; ++c) {
                unsigned int yw[8];
#pragma unroll
                for (int j = 0; j < 8; ++j) {
                    int e = mt * 16 + c * 8 + j;
                    if (e < m) {
                        int src = __shfl(nv, e);
                        yw[j] = wbuf[src * 64 + lane];
                    }
                }
#pragma unroll
                for (int j = 0; j < 8; ++j) {
                    int e = mt * 16 + c * 8 + j;
                    if (e < m) {
                        float h0 = fmaxf(bf_lo(yw[j]) + shp0, 0.0f);
                        float h1 = fmaxf(bf_hi(yw[j]) + shp1, 0.0f);
                        *(unsigned int*)&hb[(c * 8 + j) * 136 + f0] = pack_bf2(h0, h1);
                    }
                }
            }
            __builtin_amdgcn_wave_barrier();
            floatx4 a0 = {0,0,0,0}, a1 = {0,0,0,0}, a2 = {0,0,0,0}, a3 = {0,0,0,0};
#pragma unroll
            for (int ks = 0; ks < 4; ++ks) {
                short8 a = *(const short8*)&hb[(lane & 15) * 136 + ks * 32 + (lane >> 4) * 8];
                a0 = __builtin_amdgcn_mfma_f32_16x16x32_bf16(a, bfrag[0][ks], a0, 0, 0, 0);
                a1 = __builtin_amdgcn_mfma_f32_16x16x32_bf16(a, bfrag[1][ks], a1, 0, 0, 0);
                a2 = __builtin_amdgcn_mfma_f32_16x16x32_bf16(a, bfrag[2][ks], a2, 0, 0, 0);
                a3 = __builtin_amdgcn_mfma_f32_16x16x32_bf16(a, bfrag[3][ks], a3, 0, 0, 0);
            }
            __builtin_amdgcn_wave_barrier();
            int rowb = (lane >> 4) * 4;
#pragma unroll
            for (int r = 0; r < 4; ++r) {
                if (rowb + r < g) {
                    om0[r] = fmaxf(om0[r], a0[r]);
                    om1[r] = fmaxf(om1[r], a1[r]);
                    om2[r] = fmaxf(om2[r], a2[r]);
                    om3[r] = fmaxf(om3[r], a3[r]);
                }
            }
        }
        float w0 = fmaxf(fmaxf(om0[0], om0[1]), fmaxf(om0[2], om0[3]));
        float w1 = fmaxf(fmaxf(om1[0], om1[1]), fmaxf(om1[2], om1[3]));
        float w2 = fmaxf(fmaxf(om2[0], om2[1]), fmaxf(om2[2], om2[3]));
        float w3 = fmaxf(fmaxf(om3[0], om3[1]), fmaxf(om3[2], om3[3]));
        w0 = fmaxf(w0, __shfl_xor(w0, 16)); w0 = fmaxf(w0, __shfl_xor(w0, 32));
        w1 = fmaxf(w1, __shfl_xor(w1, 16)); w1 = fmaxf(w1, __shfl_xor(w1, 32));
        w2 = fmaxf(w2, __shfl_xor(w2, 16)); w2 = fmaxf(w2, __shfl_xor(w2, 32));
        w3 = fmaxf(w3, __shfl_xor(w3, 16)); w3 = fmaxf(w3, __shfl_xor(w3, 32));
        int g4 = lane >> 4;   // feature = g4*16 + (lane&15) = lane
        float vf = (g4 == 0) ? w0 : (g4 == 1) ? w1 : (g4 == 2) ? w2 : w3;
        vf += b2l;            // m==0 -> -inf: ignored by k_gather's max
        scratch[islot[q] * 64 + lane] = vf;    // plain coalesced store, no atomics
    }
}

// ---------- gather: per pixel, max(self, contiguous query slots) ------------
__launch_bounds__(256)
__global__ void k_gather(const float* __restrict__ scratch, const float* __restrict__ selfbuf,
                         const int* __restrict__ qcnt, const int* __restrict__ qstart,
                         float* __restrict__ out) {
    int tid = threadIdx.x, wave = tid >> 6, lane = tid & 63;
    int n = blockIdx.x * 4 + wave;
    int c = qcnt[n];
    if (c == 0) return;                  // out already holds the self value
    int qs = qstart[n];
    float v = selfbuf[n * 64 + lane];
    for (int i = 0; i < c; ++i)
        v = fmaxf(v, scratch[(qs + i) * 64 + lane]);
    out[(n >> 10) * 65536 + lane * 1024 + (n & 1023)] = v;
}

extern "C" void kernel_launch(void* const* d_in, const int* in_sizes, int n_in,
                              void* d_out, int out_size, void* d_ws, size_t ws_size,
                              hipStream_t stream) {
    const float* x     = (const float*)d_in[0];
    const float* pos   = (const float*)d_in[1];
    // d_in[2] = batch (unused: points are sorted, b = idx >> 10)
    const float* W1    = (const float*)d_in[3];
    const float* b1    = (const float*)d_in[4];
    const float* gamma = (const float*)d_in[5];
    const float* beta  = (const float*)d_in[6];
    const float* W2    = (const float*)d_in[7];
    const float* b2    = (const float*)d_in[8];
    float* out = (float*)d_out;
    char* ws = (char*)d_ws;
    int*   nbrs     = (int*)(ws + WS_NBRS);
    int*   nbr_cnt  = (int*)(ws + WS_NBRCNT);
    float* deg      = (float*)(ws + WS_DEG);
    float* stx      = (float*)(ws + WS_STX);
    float* sty      = (float*)(ws + WS_STY);
    float* defrep   = (float*)(ws + WS_DEFREP);
    float* scsh     = (float*)(ws + WS_SCSH);
    unsigned short* w2b = (unsigned short*)(ws + WS_W2B);
    float* partials = (float*)(ws + WS_PART);
    unsigned int* yb = (unsigned int*)(ws + WS_Y);
    float* scratch  = (float*)(ws + WS_SCRATCH);        // overlays yb (dead after k_self)
    float* bqpart   = (float*)(ws + WS_BQPART);
    unsigned int* wbuf = (unsigned int*)(ws + WS_WB);   // overlays bqpart (dead after k_nodeagg)
    int* qcnt   = (int*)(ws + WS_QCNT);
    int* qstart = (int*)(ws + WS_QSTART);
    int* qlist  = (int*)(ws + WS_QLIST);
    int* islot  = (int*)(ws + WS_ISLOT);
    float* selfbuf = (float*)(ws + WS_SELF);

    k_prep<<<32, 256, 0, stream>>>(W2, w2b, defrep);
    k_pixmap<<<32, 256, 0, stream>>>(pos, qcnt, qstart, qlist, islot);
    k_ballquery<<<512, 256, 0, stream>>>(pos, nbrs, nbr_cnt, bqpart, defrep);
    k_nodeagg<<<128, 256, 0, stream>>>(bqpart, deg, stx, sty);
    k_y<<<256, 256, 0, stream>>>(x, W1, b1, pos, deg, stx, sty, yb, partials);
    k_finalize<<<1, 256, 0, stream>>>(gamma, beta, W1, partials, defrep, scsh);
    k_self<<<NPTS / 64, 256, 0, stream>>>(yb, pos, W1, scsh, w2b, b2, wbuf, selfbuf, out);
    k_out<<<NPTS / 8, 256, 0, stream>>>(wbuf, pos, W1, scsh, w2b, b2,
                                        nbrs, nbr_cnt, islot, scratch);
    k_gather<<<NPTS / 4, 256, 0, stream>>>(scratch, selfbuf, qcnt, qstart, out);
}

// Round 8
// 276.337 us; speedup vs baseline: 1.4565x; 1.0818x over previous
//
#include <hip/hip_runtime.h>
#include <hip/hip_bf16.h>
#include <math.h>

// ---------------------------------------------------------------------------
// PointsToImage: ball-query (K=32, R=0.1) -> PointNetConv msg=[x_j, pos_j-pos_dst]
// -> Linear(66,128) -> masked-BatchNorm -> ReLU -> Linear(128,64) -> scatter-max
// into pixel nodes, output [B=32, F=64, 32, 32] fp32.
//
// R8: k_out rebuilt LDS-free. MFMA A-frag (lane L: 8 consecutive features of
// edge m=L&15) is gathered straight from wbuf as ONE dwordx4 per ks (features
// are bf16-paired per dword), h=relu(w+shp) applied in-register, MFMA fed
// directly. shp (pixel shift, bf16-paired, same layout) precomputed per node
// in k_self. Removes all per-edge LDS writes/reads/barriers and per-edge
// shuffles (1 shfl per 16-edge tile). k_prep merged into k_pixmap.
// Pipeline: k_prep(pixmap+pack) -> k_ballquery -> k_nodeagg -> k_y ->
//           k_finalize -> k_self -> k_out -> k_gather
// ---------------------------------------------------------------------------

#define NPTS   32768
#define KNB    32
#define BN_EPS 1e-5f

// workspace layout (bytes)
#define WS_NBRS     0u           // int[NPTS*KNB]      = 4194304
#define WS_NBRCNT   4194304u     // int[NPTS]          = 131072
#define WS_DEG      4325376u     // float[NPTS]        = 131072
#define WS_STX      4456448u     // float[NPTS]        = 131072
#define WS_STY      4587520u     // float[NPTS]        = 131072
#define WS_DEFREP   4718592u     // float[64*4]        = 1024
#define WS_SCSH     4719616u     // float[256]         = 1024
#define WS_W2B      4720640u     // ushort[8192]       = 16384
#define WS_PART     4737024u     // float[256*516]     = 528384
#define WS_Y        5265408u     // uint[NPTS*64]      = 8388608 (yb; dead after k_self)
#define WS_SCRATCH  5265408u     // float[NPTS*64]     = 8388608 (per-query maxima; OVERLAYS yb)
#define WS_BQPART   13654016u    // float[512*3072]    = 6291456 (consumed by k_nodeagg)
#define WS_WB       13654016u    // uint[NPTS*64]      = 8388608 (w, bf16 pairs; OVERLAYS bqpart)
#define WS_QCNT     22042624u    // int[NPTS]          = 131072
#define WS_QSTART   22173696u    // int[NPTS]          = 131072
#define WS_QLIST    22304768u    // int[NPTS]          = 131072
#define WS_ISLOT    22435840u    // int[NPTS]          = 131072
#define WS_SELF     22566912u    // float[NPTS*64]     = 8388608 (self-msg MLP out)
#define WS_SHP      30955520u    // uint[NPTS*64]      = 8388608 (shp, bf16 pairs)

typedef __attribute__((ext_vector_type(8))) short short8;
typedef __attribute__((ext_vector_type(4))) float floatx4;

__device__ __forceinline__ unsigned short f2bf(float f) {
    unsigned int u = __float_as_uint(f);
    unsigned int r = u + 0x7fffu + ((u >> 16) & 1u);   // RNE
    return (unsigned short)(r >> 16);
}
__device__ __forceinline__ float bf_lo(unsigned int w) { return __uint_as_float(w << 16); }
__device__ __forceinline__ float bf_hi(unsigned int w) { return __uint_as_float(w & 0xffff0000u); }
__device__ __forceinline__ unsigned int pack_bf2(float lo, float hi) {
    __hip_bfloat162 hh = __float22bfloat162_rn(make_float2(lo, hi));
    return *reinterpret_cast<unsigned int*>(&hh);
}

// ---------- prep: W2 B-frag pack + defrep zero + query->pixel inversion -----
__launch_bounds__(256)
__global__ void k_prep(const float* __restrict__ W2, unsigned short* __restrict__ w2b,
                       float* __restrict__ defrep, const float* __restrict__ pos,
                       int* __restrict__ qcnt, int* __restrict__ qstart,
                       int* __restrict__ qlist, int* __restrict__ islot) {
    int tid = threadIdx.x;
    int gt = blockIdx.x * 256 + tid;          // 32 blocks * 256 = 8192
    if (gt < 256) defrep[gt] = 0.0f;
    {   // W2 pack: B-frag lane L holds B[k=(L>>4)*8+j][n=L&15]
        int j  = gt & 7;
        int L  = (gt >> 3) & 63;
        int ks = (gt >> 9) & 3;
        int t4 = gt >> 11;
        int k = ks * 32 + (L >> 4) * 8 + j;
        int n = t4 * 16 + (L & 15);
        w2b[gt] = f2bf(W2[k * 64 + n]);
    }
    // pixel map for sample s = blockIdx.x
    __shared__ int cntS[1024], preS[1024], offS[1024], pixOf[1024];
    __shared__ int wtot[4];
    int s = blockIdx.x;
    int base = s << 10;
    for (int i = tid; i < 1024; i += 256) cntS[i] = 0;
    __syncthreads();
    for (int ql = tid; ql < 1024; ql += 256) {
        float2 p = *(const float2*)&pos[2 * (base + ql)];
        int row = min(max((int)(p.y * 32.0f), 0), 31);
        int col = min(max((int)(p.x * 32.0f), 0), 31);
        int pixl = row * 32 + col;
        pixOf[ql] = pixl;
        atomicAdd(&cntS[pixl], 1);
    }
    __syncthreads();
    int a0 = cntS[4 * tid], a1 = cntS[4 * tid + 1], a2 = cntS[4 * tid + 2], a3 = cntS[4 * tid + 3];
    int tsum = a0 + a1 + a2 + a3;
    int lane = tid & 63, wv = tid >> 6;
    int v = tsum;
    for (int o = 1; o < 64; o <<= 1) { int u = __shfl_up(v, o); if (lane >= o) v += u; }
    if (lane == 63) wtot[wv] = v;
    __syncthreads();
    int wbase = 0;
    for (int w = 0; w < wv; ++w) wbase += wtot[w];
    int excl = wbase + v - tsum;
    preS[4 * tid] = excl;
    preS[4 * tid + 1] = excl + a0;
    preS[4 * tid + 2] = excl + a0 + a1;
    preS[4 * tid + 3] = excl + a0 + a1 + a2;
    __syncthreads();
    for (int i = tid; i < 1024; i += 256) offS[i] = preS[i];
    __syncthreads();
    for (int ql = tid; ql < 1024; ql += 256) {
        int p = pixOf[ql];
        int slot = atomicAdd(&offS[p], 1);
        qlist[base + slot] = base + ql;
        islot[base + ql] = base + slot;
    }
    for (int i = tid; i < 1024; i += 256) {
        qcnt[base + i] = cntS[i];
        qstart[base + i] = base + preS[i];
    }
}

// --------------------------- ball query (sample-resident, atomic-free) ------
__launch_bounds__(256)
__global__ void k_ballquery(const float* __restrict__ pos,
                            int* __restrict__ nbrs, int* __restrict__ nbr_cnt,
                            float* __restrict__ bqpart, float* __restrict__ defrep) {
    __shared__ float2 poss[1024];
    __shared__ float accd[1024], accx[1024], accy[1024];
    __shared__ unsigned long long cand[4][256];
    __shared__ int cnt[4], ocnt[4];
    int tid = threadIdx.x, wave = tid >> 6, lane = tid & 63;
    int s = blockIdx.x >> 4;           // sample
    int chunk = blockIdx.x & 15;       // 16 chunks of 64 queries
    int base = s << 10;
    for (int i = tid; i < 1024; i += 256) poss[i] = *(const float2*)&pos[2 * (base + i)];
    for (int i = tid; i < 1024; i += 256) { accd[i] = 0.0f; accx[i] = 0.0f; accy[i] = 0.0f; }
    __syncthreads();
    float2 pr[16];
#pragma unroll
    for (int k = 0; k < 16; ++k) pr[k] = poss[k * 64 + lane];

    float aD = 0, aE = 0, aF = 0;
    for (int qi = 0; qi < 16; ++qi) {
        int ql = chunk * 64 + wave * 16 + qi;
        int q = base + ql;
        float2 qp = poss[ql];
        int row = min(max((int)(qp.y * 32.0f), 0), 31);
        int col = min(max((int)(qp.x * 32.0f), 0), 31);
        int pixl = row * 32 + col;
        float2 tp = poss[pixl];
        if (lane == 0) { cnt[wave] = 0; ocnt[wave] = 0; }
        __builtin_amdgcn_wave_barrier();
#pragma unroll
        for (int k = 0; k < 16; ++k) {
            float dx = pr[k].x - qp.x, dy = pr[k].y - qp.y;
            float d2 = __fadd_rn(__fmul_rn(dx, dx), __fmul_rn(dy, dy)); // no FMA contraction
            if (d2 <= 0.01f) {
                int sl = atomicAdd(&cnt[wave], 1);
                if (sl < 256)
                    cand[wave][sl] = ((unsigned long long)__float_as_uint(d2) << 32)
                                     | (unsigned int)(k * 64 + lane);
            }
        }
        __builtin_amdgcn_wave_barrier();
        int c = min(cnt[wave], 256);
        for (int i = lane; i < c; i += 64) {
            unsigned long long key = cand[wave][i];
            int rank = 0;
            for (int t = 0; t < c; ++t) rank += (cand[wave][t] < key) ? 1 : 0;
            int j = (int)(key & 0xffffffffu);
            if (rank < KNB && j != pixl) {         // top-K, then remove_self_loops
                int sl = atomicAdd(&ocnt[wave], 1);
                nbrs[q * KNB + sl] = base + j;
                float rx = poss[j].x - tp.x, ry = poss[j].y - tp.y;
                aD += rx * rx; aE += rx * ry; aF += ry * ry;
                atomicAdd(&accd[j], 1.0f);
                atomicAdd(&accx[j], tp.x);
                atomicAdd(&accy[j], tp.y);
            }
        }
        __builtin_amdgcn_wave_barrier();
        if (lane == 0) nbr_cnt[q] = ocnt[wave];
    }
#pragma unroll
    for (int o = 1; o < 64; o <<= 1) {
        aD += __shfl_xor(aD, o); aE += __shfl_xor(aE, o); aF += __shfl_xor(aF, o);
    }
    __syncthreads();
    float* pb = &bqpart[blockIdx.x * 3072];
    for (int i = tid; i < 1024; i += 256) {
        pb[i] = accd[i]; pb[1024 + i] = accx[i]; pb[2048 + i] = accy[i];
    }
    if (tid == 0) {
        int r = (blockIdx.x & 63) * 4;
        atomicAdd(&defrep[r + 0], aD);
        atomicAdd(&defrep[r + 1], aE);
        atomicAdd(&defrep[r + 2], aF);
    }
}

// ------------------- sum the 16 chunk partials per node ---------------------
__global__ void k_nodeagg(const float* __restrict__ bqpart, float* __restrict__ deg,
                          float* __restrict__ stx, float* __restrict__ sty) {
    int t = blockIdx.x * 256 + threadIdx.x;   // 128 blocks -> 32768
    int s = t >> 10, off = t & 1023;
    const float* pb = &bqpart[(s * 16) * 3072];
    float d = 0, xx = 0, yy = 0;
    for (int j = 0; j < 16; ++j) {
        d  += pb[j * 3072 + off];
        xx += pb[j * 3072 + 1024 + off];
        yy += pb[j * 3072 + 2048 + off];
    }
    deg[t] = d; stx[t] = xx; sty[t] = yy;
}

// ---------------- node GEMM1 + folded BN node-stats: y = x@W1[:64]+b1 -------
// lane owns features f0=2*lane, f1=2*lane+1. yb packed (f0 lo, f1 hi).
__launch_bounds__(256)
__global__ void k_y(const float* __restrict__ x, const float* __restrict__ W1,
                    const float* __restrict__ b1, const float* __restrict__ pos,
                    const float* __restrict__ deg, const float* __restrict__ stxA,
                    const float* __restrict__ styA,
                    unsigned int* __restrict__ yb, float* __restrict__ partials) {
    __shared__ float w1s[64 * 128];
    __shared__ float stage[4][512];
    __shared__ float lsum[515];
    int tid = threadIdx.x;
    for (int i = tid; i < 64 * 128; i += 256) w1s[i] = W1[i];
    for (int i = tid; i < 515; i += 256) lsum[i] = 0.0f;
    __syncthreads();
    int wave = tid >> 6, lane = tid & 63;
    int f0 = 2 * lane, f1 = 2 * lane + 1;
    float b10 = b1[f0], b11 = b1[f1];
    float* st = &stage[wave][0];
    float P0 = 0, Q0 = 0, R0 = 0, S0 = 0, P1 = 0, Q1 = 0, R1 = 0, S1 = 0;
    float sB = 0, sC = 0, sDeg = 0;

    for (int it = 0; it < 4; ++it) {
        int nbase = ((blockIdx.x * 4 + wave) * 4 + it) * 8;
        __builtin_amdgcn_wave_barrier();
#pragma unroll
        for (int mm = 0; mm < 8; ++mm)
            st[mm * 64 + lane] = x[(nbase + mm) * 64 + lane];
        __builtin_amdgcn_wave_barrier();
        float z0[8], z1[8];
#pragma unroll
        for (int mm = 0; mm < 8; ++mm) { z0[mm] = b10; z1[mm] = b11; }
        for (int k4 = 0; k4 < 16; ++k4) {
            float2 wv0 = *(const float2*)&w1s[(k4 * 4 + 0) * 128 + f0];
            float2 wv1 = *(const float2*)&w1s[(k4 * 4 + 1) * 128 + f0];
            float2 wv2 = *(const float2*)&w1s[(k4 * 4 + 2) * 128 + f0];
            float2 wv3 = *(const float2*)&w1s[(k4 * 4 + 3) * 128 + f0];
#pragma unroll
            for (int mm = 0; mm < 8; ++mm) {
                float4 mk = *(const float4*)&st[mm * 64 + k4 * 4];
                z0[mm] += mk.x * wv0.x + mk.y * wv1.x + mk.z * wv2.x + mk.w * wv3.x;
                z1[mm] += mk.x * wv0.y + mk.y * wv1.y + mk.z * wv2.y + mk.w * wv3.y;
            }
        }
#pragma unroll
        for (int mm = 0; mm < 8; ++mm) {
            int n = nbase + mm;
            float dg = deg[n];
            float wgt = 1.0f + dg;
            float Bn = dg * pos[2 * n]     - stxA[n];
            float Cn = dg * pos[2 * n + 1] - styA[n];
            float a = z0[mm], bq = z1[mm];
            P0 += wgt * a;  Q0 += wgt * a * a;  R0 += a * Bn;  S0 += a * Cn;
            P1 += wgt * bq; Q1 += wgt * bq * bq; R1 += bq * Bn; S1 += bq * Cn;
            sB += Bn; sC += Cn; sDeg += dg;
            yb[n * 64 + lane] = pack_bf2(a, bq);
        }
    }
    atomicAdd(&lsum[f0], P0);        atomicAdd(&lsum[f1], P1);
    atomicAdd(&lsum[128 + f0], Q0);  atomicAdd(&lsum[128 + f1], Q1);
    atomicAdd(&lsum[256 + f0], R0);  atomicAdd(&lsum[256 + f1], R1);
    atomicAdd(&lsum[384 + f0], S0);  atomicAdd(&lsum[384 + f1], S1);
    if (lane == 0) {
        atomicAdd(&lsum[512], sB);
        atomicAdd(&lsum[513], sC);
        atomicAdd(&lsum[514], sDeg);
    }
    __syncthreads();
    for (int i = tid; i < 515; i += 256) partials[blockIdx.x * 516 + i] = lsum[i];
}

// --------------------------- finalize BN scale/shift ------------------------
__global__ void k_finalize(const float* __restrict__ gamma, const float* __restrict__ beta,
                           const float* __restrict__ W1, const float* __restrict__ partials,
                           const float* __restrict__ defrep, float* __restrict__ scsh) {
    __shared__ float red[515];
    __shared__ float sDEF[3];
    int tid = threadIdx.x;    // 256
    for (int i = tid; i < 515; i += 256) {
        float s = 0;
        for (int b = 0; b < 256; ++b) s += partials[b * 516 + i];
        red[i] = s;
    }
    if (tid < 3) {
        float s = 0;
        for (int r = 0; r < 64; ++r) s += defrep[r * 4 + tid];
        sDEF[tid] = s;
    }
    __syncthreads();
    if (tid < 128) {
        int f = tid;
        float P = red[f], Q = red[128 + f], R = red[256 + f], S = red[384 + f];
        float SB = red[512], SC = red[513], SDeg = red[514];
        float u = W1[8192 + f], v = W1[8320 + f];
        float cntv = 32768.0f + SDeg;
        float mean = (P + u * SB + v * SC) / cntv;
        float E2 = (Q + 2.0f * u * R + 2.0f * v * S
                    + u * u * sDEF[0] + 2.0f * u * v * sDEF[1] + v * v * sDEF[2]) / cntv;
        float var = E2 - mean * mean;
        float sc = gamma[f] / sqrtf(var + BN_EPS);
        scsh[f] = sc;
        scsh[128 + f] = beta[f] - mean * sc;
    }
}

// ---------- self pass (MFMA) + w/shp precompute; writes out + selfbuf -------
__launch_bounds__(256)
__global__ void k_self(const unsigned int* __restrict__ yb, const float* __restrict__ pos,
                       const float* __restrict__ W1, const float* __restrict__ scsh,
                       const unsigned short* __restrict__ w2b, const float* __restrict__ b2,
                       unsigned int* __restrict__ wbuf, unsigned int* __restrict__ shpbuf,
                       float* __restrict__ selfbuf, float* __restrict__ out) {
    __shared__ unsigned short hbuf[4][16 * 136];   // 272 B row stride
    int tid = threadIdx.x, wave = tid >> 6, lane = tid & 63;
    unsigned short* hb = hbuf[wave];
    short8 bfrag[4][4];
#pragma unroll
    for (int t = 0; t < 4; ++t)
#pragma unroll
        for (int ks = 0; ks < 4; ++ks)
            bfrag[t][ks] = *(const short8*)&w2b[((t * 4 + ks) * 64 + lane) * 8];
    int f0 = 2 * lane;
    float sc0 = scsh[f0],     sh0 = scsh[128 + f0];
    float sc1 = scsh[f0 + 1], sh1 = scsh[129 + f0];
    float u0 = W1[8192 + f0], v0 = W1[8320 + f0];
    float u1 = W1[8193 + f0], v1 = W1[8321 + f0];
    float b2v0 = b2[(lane & 15)],      b2v1 = b2[16 + (lane & 15)];
    float b2v2 = b2[32 + (lane & 15)], b2v3 = b2[48 + (lane & 15)];

    int nbase = (blockIdx.x * 4 + wave) * 16;
#pragma unroll
    for (int c = 0; c < 2; ++c) {
        unsigned int yw[8];
#pragma unroll
        for (int j = 0; j < 8; ++j)
            yw[j] = yb[(nbase + c * 8 + j) * 64 + lane];
#pragma unroll
        for (int j = 0; j < 8; ++j) {
            int e = c * 8 + j;
            int nn = nbase + e;
            float y0 = bf_lo(yw[j]), y1 = bf_hi(yw[j]);
            float h0 = fmaxf(y0 * sc0 + sh0, 0.0f);
            float h1 = fmaxf(y1 * sc1 + sh1, 0.0f);
            *(unsigned int*)&hb[e * 136 + f0] = pack_bf2(h0, h1);
            float px = pos[2 * nn], py = pos[2 * nn + 1];
            float ts0 = (px * u0 + py * v0) * sc0;
            float ts1 = (px * u1 + py * v1) * sc1;
            wbuf[nn * 64 + lane]   = pack_bf2(y0 * sc0 + ts0, y1 * sc1 + ts1);
            shpbuf[nn * 64 + lane] = pack_bf2(sh0 - ts0, sh1 - ts1);
        }
    }
    __builtin_amdgcn_wave_barrier();
    floatx4 acc0 = {0,0,0,0}, acc1 = {0,0,0,0}, acc2 = {0,0,0,0}, acc3 = {0,0,0,0};
#pragma unroll
    for (int ks = 0; ks < 4; ++ks) {
        short8 a = *(const short8*)&hb[(lane & 15) * 136 + ks * 32 + (lane >> 4) * 8];
        acc0 = __builtin_amdgcn_mfma_f32_16x16x32_bf16(a, bfrag[0][ks], acc0, 0, 0, 0);
        acc1 = __builtin_amdgcn_mfma_f32_16x16x32_bf16(a, bfrag[1][ks], acc1, 0, 0, 0);
        acc2 = __builtin_amdgcn_mfma_f32_16x16x32_bf16(a, bfrag[2][ks], acc2, 0, 0, 0);
        acc3 = __builtin_amdgcn_mfma_f32_16x16x32_bf16(a, bfrag[3][ks], acc3, 0, 0, 0);
    }
    int nrow = nbase + (lane >> 4) * 4;
#pragma unroll
    for (int r = 0; r < 4; ++r) {
        int n = nrow + r;
        int obase = (n >> 10) * 65536 + (n & 1023);
        float o0 = acc0[r] + b2v0, o1 = acc1[r] + b2v1;
        float o2 = acc2[r] + b2v2, o3 = acc3[r] + b2v3;
        out[obase + ((lane & 15)) * 1024]      = o0;
        out[obase + (16 + (lane & 15)) * 1024] = o1;
        out[obase + (32 + (lane & 15)) * 1024] = o2;
        out[obase + (48 + (lane & 15)) * 1024] = o3;
        selfbuf[n * 64 + (lane & 15)]      = o0;   // contiguous copy for k_gather
        selfbuf[n * 64 + 16 + (lane & 15)] = o1;
        selfbuf[n * 64 + 32 + (lane & 15)] = o2;
        selfbuf[n * 64 + 48 + (lane & 15)] = o3;
    }
}

// ---------- neighbor pass: LDS-free, A-frag gathered in-layout --------------
__launch_bounds__(256)
__global__ void k_out(const unsigned int* __restrict__ wbuf,
                      const unsigned int* __restrict__ shpbuf,
                      const float* __restrict__ pos,
                      const unsigned short* __restrict__ w2b, const float* __restrict__ b2,
                      const int* __restrict__ nbrs, const int* __restrict__ nbr_cnt,
                      const int* __restrict__ islot, float* __restrict__ scratch) {
    int tid = threadIdx.x, wave = tid >> 6, lane = tid & 63;
    short8 bfrag[4][4];
#pragma unroll
    for (int t = 0; t < 4; ++t)
#pragma unroll
        for (int ks = 0; ks < 4; ++ks)
            bfrag[t][ks] = *(const short8*)&w2b[((t * 4 + ks) * 64 + lane) * 8];
    float b2l = b2[lane];
    int em = lane & 15;                  // edge-in-tile this lane's A-frag covers
    int koff = (lane >> 4) * 4;          // dword offset of this lane's 8 features
    int wid = blockIdx.x * 4 + wave;     // 16384 waves, 2 queries each

    for (int qi = 0; qi < 2; ++qi) {
        int q = wid * 2 + qi;
        int m = nbr_cnt[q];              // m <= 32
        int b = q >> 10;
        float qx = pos[2 * q], qy = pos[2 * q + 1];
        int row = min(max((int)(qy * 32.0f), 0), 31);
        int col = min(max((int)(qx * 32.0f), 0), 31);
        int pixq = (b << 10) + row * 32 + col;
        // per-query shp (bf16 pairs), 4 uint4 = this lane's 32 features
        uint4 sv0 = *(const uint4*)&shpbuf[pixq * 64 + 0 * 16 + koff];
        uint4 sv1 = *(const uint4*)&shpbuf[pixq * 64 + 1 * 16 + koff];
        uint4 sv2 = *(const uint4*)&shpbuf[pixq * 64 + 2 * 16 + koff];
        uint4 sv3 = *(const uint4*)&shpbuf[pixq * 64 + 3 * 16 + koff];
        int nv = (lane < m) ? nbrs[q * KNB + lane] : 0;
        float om0[4], om1[4], om2[4], om3[4];
#pragma unroll
        for (int r = 0; r < 4; ++r) { om0[r] = -INFINITY; om1[r] = -INFINITY; om2[r] = -INFINITY; om3[r] = -INFINITY; }

        for (int mt = 0; mt * 16 < m; ++mt) {       // at most 2 tiles
            int src = __shfl(nv, mt * 16 + em);
            const unsigned int* wp = &wbuf[src * 64 + koff];
            floatx4 a0 = {0,0,0,0}, a1 = {0,0,0,0}, a2 = {0,0,0,0}, a3 = {0,0,0,0};
#pragma unroll
            for (int ks = 0; ks < 4; ++ks) {
                uint4 wv = *(const uint4*)&wp[ks * 16];
                uint4 sv = (ks == 0) ? sv0 : (ks == 1) ? sv1 : (ks == 2) ? sv2 : sv3;
                union { unsigned int u[4]; short8 s8; } af;
#pragma unroll
                for (int qd = 0; qd < 4; ++qd) {
                    unsigned int wd = (qd == 0) ? wv.x : (qd == 1) ? wv.y : (qd == 2) ? wv.z : wv.w;
                    unsigned int sd = (qd == 0) ? sv.x : (qd == 1) ? sv.y : (qd == 2) ? sv.z : sv.w;
                    float lo = fmaxf(bf_lo(wd) + bf_lo(sd), 0.0f);
                    float hi = fmaxf(bf_hi(wd) + bf_hi(sd), 0.0f);
                    af.u[qd] = pack_bf2(lo, hi);
                }
                a0 = __builtin_amdgcn_mfma_f32_16x16x32_bf16(af.s8, bfrag[0][ks], a0, 0, 0, 0);
                a1 = __builtin_amdgcn_mfma_f32_16x16x32_bf16(af.s8, bfrag[1][ks], a1, 0, 0, 0);
                a2 = __builtin_amdgcn_mfma_f32_16x16x32_bf16(af.s8, bfrag[2][ks], a2, 0, 0, 0);
                a3 = __builtin_amdgcn_mfma_f32_16x16x32_bf16(af.s8, bfrag[3][ks], a3, 0, 0, 0);
            }
            int rowb = (lane >> 4) * 4;
#pragma unroll
            for (int r = 0; r < 4; ++r) {
                int e = mt * 16 + rowb + r;
                if (e < m) {
                    om0[r] = fmaxf(om0[r], a0[r]);
                    om1[r] = fmaxf(om1[r], a1[r]);
                    om2[r] = fmaxf(om2[r], a2[r]);
                    om3[r] = fmaxf(om3[r], a3[r]);
                }
            }
        }
        float w0 = fmaxf(fmaxf(om0[0], om0[1]), fmaxf(om0[2], om0[3]));
        float w1 = fmaxf(fmaxf(om1[0], om1[1]), fmaxf(om1[2], om1[3]));
        float w2 = fmaxf(fmaxf(om2[0], om2[1]), fmaxf(om2[2], om2[3]));
        float w3 = fmaxf(fmaxf(om3[0], om3[1]), fmaxf(om3[2], om3[3]));
        w0 = fmaxf(w0, __shfl_xor(w0, 16)); w0 = fmaxf(w0, __shfl_xor(w0, 32));
        w1 = fmaxf(w1, __shfl_xor(w1, 16)); w1 = fmaxf(w1, __shfl_xor(w1, 32));
        w2 = fmaxf(w2, __shfl_xor(w2, 16)); w2 = fmaxf(w2, __shfl_xor(w2, 32));
        w3 = fmaxf(w3, __shfl_xor(w3, 16)); w3 = fmaxf(w3, __shfl_xor(w3, 32));
        int g4 = lane >> 4;   // feature = g4*16 + (lane&15) = lane
        float vf = (g4 == 0) ? w0 : (g4 == 1) ? w1 : (g4 == 2) ? w2 : w3;
        vf += b2l;            // m==0 -> -inf: ignored by k_gather's max
        scratch[islot[q] * 64 + lane] = vf;    // plain coalesced store, no atomics
    }
}

// ---------- gather: per pixel, max(self, contiguous query slots) ------------
__launch_bounds__(256)
__global__ void k_gather(const float* __restrict__ scratch, const float* __restrict__ selfbuf,
                         const int* __restrict__ qcnt, const int* __restrict__ qstart,
                         float* __restrict__ out) {
    int tid = threadIdx.x, wave = tid >> 6, lane = tid & 63;
    int n = blockIdx.x * 4 + wave;
    int c = qcnt[n];
    if (c == 0) return;                  // out already holds the self value
    int qs = qstart[n];
    float v = selfbuf[n * 64 + lane];
    for (int i = 0; i < c; ++i)
        v = fmaxf(v, scratch[(qs + i) * 64 + lane]);
    out[(n >> 10) * 65536 + lane * 1024 + (n & 1023)] = v;
}

extern "C" void kernel_launch(void* const* d_in, const int* in_sizes, int n_in,
                              void* d_out, int out_size, void* d_ws, size_t ws_size,
                              hipStream_t stream) {
    const float* x     = (const float*)d_in[0];
    const float* pos   = (const float*)d_in[1];
    // d_in[2] = batch (unused: points are sorted, b = idx >> 10)
    const float* W1    = (const float*)d_in[3];
    const float* b1    = (const float*)d_in[4];
    const float* gamma = (const float*)d_in[5];
    const float* beta  = (const float*)d_in[6];
    const float* W2    = (const float*)d_in[7];
    const float* b2    = (const float*)d_in[8];
    float* out = (float*)d_out;
    char* ws = (char*)d_ws;
    int*   nbrs     = (int*)(ws + WS_NBRS);
    int*   nbr_cnt  = (int*)(ws + WS_NBRCNT);
    float* deg      = (float*)(ws + WS_DEG);
    float* stx      = (float*)(ws + WS_STX);
    float* sty      = (float*)(ws + WS_STY);
    float* defrep   = (float*)(ws + WS_DEFREP);
    float* scsh     = (float*)(ws + WS_SCSH);
    unsigned short* w2b = (unsigned short*)(ws + WS_W2B);
    float* partials = (float*)(ws + WS_PART);
    unsigned int* yb = (unsigned int*)(ws + WS_Y);
    float* scratch  = (float*)(ws + WS_SCRATCH);        // overlays yb (dead after k_self)
    float* bqpart   = (float*)(ws + WS_BQPART);
    unsigned int* wbuf = (unsigned int*)(ws + WS_WB);   // overlays bqpart (dead after k_nodeagg)
    int* qcnt   = (int*)(ws + WS_QCNT);
    int* qstart = (int*)(ws + WS_QSTART);
    int* qlist  = (int*)(ws + WS_QLIST);
    int* islot  = (int*)(ws + WS_ISLOT);
    float* selfbuf = (float*)(ws + WS_SELF);
    unsigned int* shpbuf = (unsigned int*)(ws + WS_SHP);

    k_prep<<<32, 256, 0, stream>>>(W2, w2b, defrep, pos, qcnt, qstart, qlist, islot);
    k_ballquery<<<512, 256, 0, stream>>>(pos, nbrs, nbr_cnt, bqpart, defrep);
    k_nodeagg<<<128, 256, 0, stream>>>(bqpart, deg, stx, sty);
    k_y<<<256, 256, 0, stream>>>(x, W1, b1, pos, deg, stx, sty, yb, partials);
    k_finalize<<<1, 256, 0, stream>>>(gamma, beta, W1, partials, defrep, scsh);
    k_self<<<NPTS / 64, 256, 0, stream>>>(yb, pos, W1, scsh, w2b, b2, wbuf, shpbuf, selfbuf, out);
    k_out<<<NPTS / 8, 256, 0, stream>>>(wbuf, shpbuf, pos, w2b, b2,
                                        nbrs, nbr_cnt, islot, scratch);
    k_gather<<<NPTS / 4, 256, 0, stream>>>(scratch, selfbuf, qcnt, qstart, out);
}

// Round 9
// 249.422 us; speedup vs baseline: 1.6136x; 1.1079x over previous
//
#include <hip/hip_runtime.h>
#include <hip/hip_bf16.h>
#include <math.h>

// ---------------------------------------------------------------------------
// PointsToImage: ball-query (K=32, R=0.1) -> PointNetConv msg=[x_j, pos_j-pos_dst]
// -> Linear(66,128) -> masked-BatchNorm -> ReLU -> Linear(128,64) -> scatter-max
// into pixel nodes, output [B=32, F=64, 32, 32] fp32.
//
// R9: ballquery rewritten atomic-free via ballot-prefix compaction (R8: ~1000
// serialized same-address LDS atomics/wave = 70 us). cnt/osel are scalar
// running counts; slots come from __ballot + popcll prefix. Rank phase skipped
// when cnt<=K (half of queries). 1024 blocks (32 queries each, 8/wave) for
// 4 blocks/CU. bqpart (12.6 MB, dead after k_nodeagg) overlays selfbuf+shpbuf.
// Pipeline: k_prep(pixmap+pack) -> k_ballquery -> k_nodeagg -> k_y ->
//           k_finalize -> k_self -> k_out -> k_gather
// ---------------------------------------------------------------------------

#define NPTS   32768
#define KNB    32
#define BN_EPS 1e-5f

// workspace layout (bytes)
#define WS_NBRS     0u           // int[NPTS*KNB]      = 4194304
#define WS_NBRCNT   4194304u     // int[NPTS]          = 131072
#define WS_DEG      4325376u     // float[NPTS]        = 131072
#define WS_STX      4456448u     // float[NPTS]        = 131072
#define WS_STY      4587520u     // float[NPTS]        = 131072
#define WS_DEFREP   4718592u     // float[64*4]        = 1024
#define WS_SCSH     4719616u     // float[256]         = 1024
#define WS_W2B      4720640u     // ushort[8192]       = 16384
#define WS_PART     4737024u     // float[256*516]     = 528384
#define WS_Y        5265408u     // uint[NPTS*64]      = 8388608 (yb; dead after k_self)
#define WS_SCRATCH  5265408u     // float[NPTS*64]     = 8388608 (OVERLAYS yb)
#define WS_WB       13654016u    // uint[NPTS*64]      = 8388608 (w, bf16 pairs)
#define WS_QCNT     22042624u    // int[NPTS]          = 131072
#define WS_QSTART   22173696u    // int[NPTS]          = 131072
#define WS_QLIST    22304768u    // int[NPTS]          = 131072
#define WS_ISLOT    22435840u    // int[NPTS]          = 131072
#define WS_SELF     22566912u    // float[NPTS*64]     = 8388608
#define WS_SHP      30955520u    // uint[NPTS*64]      = 8388608
#define WS_BQPART   22566912u    // float[1024*3072]   = 12582912 (OVERLAYS self+shp;
                                 //   dead after k_nodeagg, before k_self writes them)

typedef __attribute__((ext_vector_type(8))) short short8;
typedef __attribute__((ext_vector_type(4))) float floatx4;

__device__ __forceinline__ unsigned short f2bf(float f) {
    unsigned int u = __float_as_uint(f);
    unsigned int r = u + 0x7fffu + ((u >> 16) & 1u);   // RNE
    return (unsigned short)(r >> 16);
}
__device__ __forceinline__ float bf_lo(unsigned int w) { return __uint_as_float(w << 16); }
__device__ __forceinline__ float bf_hi(unsigned int w) { return __uint_as_float(w & 0xffff0000u); }
__device__ __forceinline__ unsigned int pack_bf2(float lo, float hi) {
    __hip_bfloat162 hh = __float22bfloat162_rn(make_float2(lo, hi));
    return *reinterpret_cast<unsigned int*>(&hh);
}

// ---------- prep: W2 B-frag pack + defrep zero + query->pixel inversion -----
__launch_bounds__(256)
__global__ void k_prep(const float* __restrict__ W2, unsigned short* __restrict__ w2b,
                       float* __restrict__ defrep, const float* __restrict__ pos,
                       int* __restrict__ qcnt, int* __restrict__ qstart,
                       int* __restrict__ qlist, int* __restrict__ islot) {
    int tid = threadIdx.x;
    int gt = blockIdx.x * 256 + tid;          // 32 blocks * 256 = 8192
    if (gt < 256) defrep[gt] = 0.0f;
    {   // W2 pack: B-frag lane L holds B[k=(L>>4)*8+j][n=L&15]
        int j  = gt & 7;
        int L  = (gt >> 3) & 63;
        int ks = (gt >> 9) & 3;
        int t4 = gt >> 11;
        int k = ks * 32 + (L >> 4) * 8 + j;
        int n = t4 * 16 + (L & 15);
        w2b[gt] = f2bf(W2[k * 64 + n]);
    }
    // pixel map for sample s = blockIdx.x
    __shared__ int cntS[1024], preS[1024], offS[1024], pixOf[1024];
    __shared__ int wtot[4];
    int s = blockIdx.x;
    int base = s << 10;
    for (int i = tid; i < 1024; i += 256) cntS[i] = 0;
    __syncthreads();
    for (int ql = tid; ql < 1024; ql += 256) {
        float2 p = *(const float2*)&pos[2 * (base + ql)];
        int row = min(max((int)(p.y * 32.0f), 0), 31);
        int col = min(max((int)(p.x * 32.0f), 0), 31);
        int pixl = row * 32 + col;
        pixOf[ql] = pixl;
        atomicAdd(&cntS[pixl], 1);
    }
    __syncthreads();
    int a0 = cntS[4 * tid], a1 = cntS[4 * tid + 1], a2 = cntS[4 * tid + 2], a3 = cntS[4 * tid + 3];
    int tsum = a0 + a1 + a2 + a3;
    int lane = tid & 63, wv = tid >> 6;
    int v = tsum;
    for (int o = 1; o < 64; o <<= 1) { int u = __shfl_up(v, o); if (lane >= o) v += u; }
    if (lane == 63) wtot[wv] = v;
    __syncthreads();
    int wbase = 0;
    for (int w = 0; w < wv; ++w) wbase += wtot[w];
    int excl = wbase + v - tsum;
    preS[4 * tid] = excl;
    preS[4 * tid + 1] = excl + a0;
    preS[4 * tid + 2] = excl + a0 + a1;
    preS[4 * tid + 3] = excl + a0 + a1 + a2;
    __syncthreads();
    for (int i = tid; i < 1024; i += 256) offS[i] = preS[i];
    __syncthreads();
    for (int ql = tid; ql < 1024; ql += 256) {
        int p = pixOf[ql];
        int slot = atomicAdd(&offS[p], 1);
        qlist[base + slot] = base + ql;
        islot[base + ql] = base + slot;
    }
    for (int i = tid; i < 1024; i += 256) {
        qcnt[base + i] = cntS[i];
        qstart[base + i] = base + preS[i];
    }
}

// ------------- ball query: ballot-prefix compaction, zero counter atomics ---
// 1024 blocks = 32 samples x 32 chunks x 32 queries (8 queries/wave).
// Exact K-smallest-within-radius, (d2,idx) tie-break via packed u64 keys;
// d2 arithmetic matches reference bit-exactly (unfused fp32 mul/add).
__launch_bounds__(256)
__global__ void k_ballquery(const float* __restrict__ pos,
                            int* __restrict__ nbrs, int* __restrict__ nbr_cnt,
                            float* __restrict__ bqpart, float* __restrict__ defrep) {
    __shared__ float2 poss[1024];
    __shared__ float accd[1024], accx[1024], accy[1024];
    __shared__ unsigned long long cand[4][256];
    int tid = threadIdx.x, wave = tid >> 6, lane = tid & 63;
    int s = blockIdx.x >> 5;           // sample
    int chunk = blockIdx.x & 31;       // 32 chunks of 32 queries
    int base = s << 10;
    for (int i = tid; i < 1024; i += 256) poss[i] = *(const float2*)&pos[2 * (base + i)];
    for (int i = tid; i < 1024; i += 256) { accd[i] = 0.0f; accx[i] = 0.0f; accy[i] = 0.0f; }
    __syncthreads();
    float2 pr[16];
#pragma unroll
    for (int k = 0; k < 16; ++k) pr[k] = poss[k * 64 + lane];
    unsigned long long lb = (1ull << lane) - 1ull;   // bits below this lane

    float aD = 0, aE = 0, aF = 0;
    for (int qi = 0; qi < 8; ++qi) {
        int ql = chunk * 32 + wave * 8 + qi;
        int q = base + ql;
        float2 qp = poss[ql];
        int row = min(max((int)(qp.y * 32.0f), 0), 31);
        int col = min(max((int)(qp.x * 32.0f), 0), 31);
        int pixl = row * 32 + col;
        float2 tp = poss[pixl];
        int cnt = 0;
        __builtin_amdgcn_wave_barrier();
#pragma unroll
        for (int k = 0; k < 16; ++k) {
            float dx = pr[k].x - qp.x, dy = pr[k].y - qp.y;
            float d2 = __fadd_rn(__fmul_rn(dx, dx), __fmul_rn(dy, dy)); // no FMA contraction
            bool pred = (d2 <= 0.01f);
            unsigned long long mask = __ballot(pred);
            if (pred) {
                int slot = cnt + (int)__popcll(mask & lb);
                if (slot < 256)
                    cand[wave][slot] = ((unsigned long long)__float_as_uint(d2) << 32)
                                       | (unsigned int)(k * 64 + lane);
            }
            cnt += (int)__popcll(mask);
        }
        cnt = min(cnt, 256);
        __builtin_amdgcn_wave_barrier();
        int osel = 0;
        for (int cb = 0; cb < cnt; cb += 64) {
            int i = cb + lane;
            bool sel = false;
            int j = 0;
            if (i < cnt) {
                unsigned long long key = cand[wave][i];
                j = (int)(key & 0xffffffffu);
                if (cnt <= KNB) {
                    sel = (j != pixl);                 // all in-radius are top-K
                } else {
                    int rank = 0;
                    for (int t = 0; t < cnt; ++t) rank += (cand[wave][t] < key) ? 1 : 0;
                    sel = (rank < KNB) && (j != pixl); // top-K, then remove_self_loops
                }
            }
            unsigned long long mask = __ballot(sel);
            if (sel) {
                int slot = osel + (int)__popcll(mask & lb);
                nbrs[q * KNB + slot] = base + j;
                float rx = poss[j].x - tp.x, ry = poss[j].y - tp.y;
                aD += rx * rx; aE += rx * ry; aF += ry * ry;
                atomicAdd(&accd[j], 1.0f);
                atomicAdd(&accx[j], tp.x);
                atomicAdd(&accy[j], tp.y);
            }
            osel += (int)__popcll(mask);
        }
        if (lane == 0) nbr_cnt[q] = osel;
    }
#pragma unroll
    for (int o = 1; o < 64; o <<= 1) {
        aD += __shfl_xor(aD, o); aE += __shfl_xor(aE, o); aF += __shfl_xor(aF, o);
    }
    __syncthreads();
    float* pb = &bqpart[blockIdx.x * 3072];
    for (int i = tid; i < 1024; i += 256) {
        pb[i] = accd[i]; pb[1024 + i] = accx[i]; pb[2048 + i] = accy[i];
    }
    if (tid == 0) {
        int r = (blockIdx.x & 63) * 4;
        atomicAdd(&defrep[r + 0], aD);
        atomicAdd(&defrep[r + 1], aE);
        atomicAdd(&defrep[r + 2], aF);
    }
}

// ------------------- sum the 32 chunk partials per node ---------------------
__global__ void k_nodeagg(const float* __restrict__ bqpart, float* __restrict__ deg,
                          float* __restrict__ stx, float* __restrict__ sty) {
    int t = blockIdx.x * 256 + threadIdx.x;   // 128 blocks -> 32768
    int s = t >> 10, off = t & 1023;
    const float* pb = &bqpart[(s * 32) * 3072];
    float d = 0, xx = 0, yy = 0;
    for (int j = 0; j < 32; ++j) {
        d  += pb[j * 3072 + off];
        xx += pb[j * 3072 + 1024 + off];
        yy += pb[j * 3072 + 2048 + off];
    }
    deg[t] = d; stx[t] = xx; sty[t] = yy;
}

// ---------------- node GEMM1 + folded BN node-stats: y = x@W1[:64]+b1 -------
// lane owns features f0=2*lane, f1=2*lane+1. yb packed (f0 lo, f1 hi).
__launch_bounds__(256)
__global__ void k_y(const float* __restrict__ x, const float* __restrict__ W1,
                    const float* __restrict__ b1, const float* __restrict__ pos,
                    const float* __restrict__ deg, const float* __restrict__ stxA,
                    const float* __restrict__ styA,
                    unsigned int* __restrict__ yb, float* __restrict__ partials) {
    __shared__ float w1s[64 * 128];
    __shared__ float stage[4][512];
    __shared__ float lsum[515];
    int tid = threadIdx.x;
    for (int i = tid; i < 64 * 128; i += 256) w1s[i] = W1[i];
    for (int i = tid; i < 515; i += 256) lsum[i] = 0.0f;
    __syncthreads();
    int wave = tid >> 6, lane = tid & 63;
    int f0 = 2 * lane, f1 = 2 * lane + 1;
    float b10 = b1[f0], b11 = b1[f1];
    float* st = &stage[wave][0];
    float P0 = 0, Q0 = 0, R0 = 0, S0 = 0, P1 = 0, Q1 = 0, R1 = 0, S1 = 0;
    float sB = 0, sC = 0, sDeg = 0;

    for (int it = 0; it < 4; ++it) {
        int nbase = ((blockIdx.x * 4 + wave) * 4 + it) * 8;
        __builtin_amdgcn_wave_barrier();
#pragma unroll
        for (int mm = 0; mm < 8; ++mm)
            st[mm * 64 + lane] = x[(nbase + mm) * 64 + lane];
        __builtin_amdgcn_wave_barrier();
        float z0[8], z1[8];
#pragma unroll
        for (int mm = 0; mm < 8; ++mm) { z0[mm] = b10; z1[mm] = b11; }
        for (int k4 = 0; k4 < 16; ++k4) {
            float2 wv0 = *(const float2*)&w1s[(k4 * 4 + 0) * 128 + f0];
            float2 wv1 = *(const float2*)&w1s[(k4 * 4 + 1) * 128 + f0];
            float2 wv2 = *(const float2*)&w1s[(k4 * 4 + 2) * 128 + f0];
            float2 wv3 = *(const float2*)&w1s[(k4 * 4 + 3) * 128 + f0];
#pragma unroll
            for (int mm = 0; mm < 8; ++mm) {
                float4 mk = *(const float4*)&st[mm * 64 + k4 * 4];
                z0[mm] += mk.x * wv0.x + mk.y * wv1.x + mk.z * wv2.x + mk.w * wv3.x;
                z1[mm] += mk.x * wv0.y + mk.y * wv1.y + mk.z * wv2.y + mk.w * wv3.y;
            }
        }
#pragma unroll
        for (int mm = 0; mm < 8; ++mm) {
            int n = nbase + mm;
            float dg = deg[n];
            float wgt = 1.0f + dg;
            float Bn = dg * pos[2 * n]     - stxA[n];
            float Cn = dg * pos[2 * n + 1] - styA[n];
            float a = z0[mm], bq = z1[mm];
            P0 += wgt * a;  Q0 += wgt * a * a;  R0 += a * Bn;  S0 += a * Cn;
            P1 += wgt * bq; Q1 += wgt * bq * bq; R1 += bq * Bn; S1 += bq * Cn;
            sB += Bn; sC += Cn; sDeg += dg;
            yb[n * 64 + lane] = pack_bf2(a, bq);
        }
    }
    atomicAdd(&lsum[f0], P0);        atomicAdd(&lsum[f1], P1);
    atomicAdd(&lsum[128 + f0], Q0);  atomicAdd(&lsum[128 + f1], Q1);
    atomicAdd(&lsum[256 + f0], R0);  atomicAdd(&lsum[256 + f1], R1);
    atomicAdd(&lsum[384 + f0], S0);  atomicAdd(&lsum[384 + f1], S1);
    if (lane == 0) {
        atomicAdd(&lsum[512], sB);
        atomicAdd(&lsum[513], sC);
        atomicAdd(&lsum[514], sDeg);
    }
    __syncthreads();
    for (int i = tid; i < 515; i += 256) partials[blockIdx.x * 516 + i] = lsum[i];
}

// --------------------------- finalize BN scale/shift ------------------------
__global__ void k_finalize(const float* __restrict__ gamma, const float* __restrict__ beta,
                           const float* __restrict__ W1, const float* __restrict__ partials,
                           const float* __restrict__ defrep, float* __restrict__ scsh) {
    __shared__ float red[515];
    __shared__ float sDEF[3];
    int tid = threadIdx.x;    // 256
    for (int i = tid; i < 515; i += 256) {
        float s = 0;
        for (int b = 0; b < 256; ++b) s += partials[b * 516 + i];
        red[i] = s;
    }
    if (tid < 3) {
        float s = 0;
        for (int r = 0; r < 64; ++r) s += defrep[r * 4 + tid];
        sDEF[tid] = s;
    }
    __syncthreads();
    if (tid < 128) {
        int f = tid;
        float P = red[f], Q = red[128 + f], R = red[256 + f], S = red[384 + f];
        float SB = red[512], SC = red[513], SDeg = red[514];
        float u = W1[8192 + f], v = W1[8320 + f];
        float cntv = 32768.0f + SDeg;
        float mean = (P + u * SB + v * SC) / cntv;
        float E2 = (Q + 2.0f * u * R + 2.0f * v * S
                    + u * u * sDEF[0] + 2.0f * u * v * sDEF[1] + v * v * sDEF[2]) / cntv;
        float var = E2 - mean * mean;
        float sc = gamma[f] / sqrtf(var + BN_EPS);
        scsh[f] = sc;
        scsh[128 + f] = beta[f] - mean * sc;
    }
}

// ---------- self pass (MFMA) + w/shp precompute; writes out + selfbuf -------
__launch_bounds__(256)
__global__ void k_self(const unsigned int* __restrict__ yb, const float* __restrict__ pos,
                       const float* __restrict__ W1, const float* __restrict__ scsh,
                       const unsigned short* __restrict__ w2b, const float* __restrict__ b2,
                       unsigned int* __restrict__ wbuf, unsigned int* __restrict__ shpbuf,
                       float* __restrict__ selfbuf, float* __restrict__ out) {
    __shared__ unsigned short hbuf[4][16 * 136];   // 272 B row stride
    int tid = threadIdx.x, wave = tid >> 6, lane = tid & 63;
    unsigned short* hb = hbuf[wave];
    short8 bfrag[4][4];
#pragma unroll
    for (int t = 0; t < 4; ++t)
#pragma unroll
        for (int ks = 0; ks < 4; ++ks)
            bfrag[t][ks] = *(const short8*)&w2b[((t * 4 + ks) * 64 + lane) * 8];
    int f0 = 2 * lane;
    float sc0 = scsh[f0],     sh0 = scsh[128 + f0];
    float sc1 = scsh[f0 + 1], sh1 = scsh[129 + f0];
    float u0 = W1[8192 + f0], v0 = W1[8320 + f0];
    float u1 = W1[8193 + f0], v1 = W1[8321 + f0];
    float b2v0 = b2[(lane & 15)],      b2v1 = b2[16 + (lane & 15)];
    float b2v2 = b2[32 + (lane & 15)], b2v3 = b2[48 + (lane & 15)];

    int nbase = (blockIdx.x * 4 + wave) * 16;
#pragma unroll
    for (int c = 0; c < 2; ++c) {
        unsigned int yw[8];
#pragma unroll
        for (int j = 0; j < 8; ++j)
            yw[j] = yb[(nbase + c * 8 + j) * 64 + lane];
#pragma unroll
        for (int j = 0; j < 8; ++j) {
            int e = c * 8 + j;
            int nn = nbase + e;
            float y0 = bf_lo(yw[j]), y1 = bf_hi(yw[j]);
            float h0 = fmaxf(y0 * sc0 + sh0, 0.0f);
            float h1 = fmaxf(y1 * sc1 + sh1, 0.0f);
            *(unsigned int*)&hb[e * 136 + f0] = pack_bf2(h0, h1);
            float px = pos[2 * nn], py = pos[2 * nn + 1];
            float ts0 = (px * u0 + py * v0) * sc0;
            float ts1 = (px * u1 + py * v1) * sc1;
            wbuf[nn * 64 + lane]   = pack_bf2(y0 * sc0 + ts0, y1 * sc1 + ts1);
            shpbuf[nn * 64 + lane] = pack_bf2(sh0 - ts0, sh1 - ts1);
        }
    }
    __builtin_amdgcn_wave_barrier();
    floatx4 acc0 = {0,0,0,0}, acc1 = {0,0,0,0}, acc2 = {0,0,0,0}, acc3 = {0,0,0,0};
#pragma unroll
    for (int ks = 0; ks < 4; ++ks) {
        short8 a = *(const short8*)&hb[(lane & 15) * 136 + ks * 32 + (lane >> 4) * 8];
        acc0 = __builtin_amdgcn_mfma_f32_16x16x32_bf16(a, bfrag[0][ks], acc0, 0, 0, 0);
        acc1 = __builtin_amdgcn_mfma_f32_16x16x32_bf16(a, bfrag[1][ks], acc1, 0, 0, 0);
        acc2 = __builtin_amdgcn_mfma_f32_16x16x32_bf16(a, bfrag[2][ks], acc2, 0, 0, 0);
        acc3 = __builtin_amdgcn_mfma_f32_16x16x32_bf16(a, bfrag[3][ks], acc3, 0, 0, 0);
    }
    int nrow = nbase + (lane >> 4) * 4;
#pragma unroll
    for (int r = 0; r < 4; ++r) {
        int n = nrow + r;
        int obase = (n >> 10) * 65536 + (n & 1023);
        float o0 = acc0[r] + b2v0, o1 = acc1[r] + b2v1;
        float o2 = acc2[r] + b2v2, o3 = acc3[r] + b2v3;
        out[obase + ((lane & 15)) * 1024]      = o0;
        out[obase + (16 + (lane & 15)) * 1024] = o1;
        out[obase + (32 + (lane & 15)) * 1024] = o2;
        out[obase + (48 + (lane & 15)) * 1024] = o3;
        selfbuf[n * 64 + (lane & 15)]      = o0;   // contiguous copy for k_gather
        selfbuf[n * 64 + 16 + (lane & 15)] = o1;
        selfbuf[n * 64 + 32 + (lane & 15)] = o2;
        selfbuf[n * 64 + 48 + (lane & 15)] = o3;
    }
}

// ---------- neighbor pass: LDS-free, A-frag gathered in-layout --------------
__launch_bounds__(256)
__global__ void k_out(const unsigned int* __restrict__ wbuf,
                      const unsigned int* __restrict__ shpbuf,
                      const float* __restrict__ pos,
                      const unsigned short* __restrict__ w2b, const float* __restrict__ b2,
                      const int* __restrict__ nbrs, const int* __restrict__ nbr_cnt,
                      const int* __restrict__ islot, float* __restrict__ scratch) {
    int tid = threadIdx.x, wave = tid >> 6, lane = tid & 63;
    short8 bfrag[4][4];
#pragma unroll
    for (int t = 0; t < 4; ++t)
#pragma unroll
        for (int ks = 0; ks < 4; ++ks)
            bfrag[t][ks] = *(const short8*)&w2b[((t * 4 + ks) * 64 + lane) * 8];
    float b2l = b2[lane];
    int em = lane & 15;                  // edge-in-tile this lane's A-frag covers
    int koff = (lane >> 4) * 4;          // dword offset of this lane's 8 features
    int wid = blockIdx.x * 4 + wave;     // 16384 waves, 2 queries each

    for (int qi = 0; qi < 2; ++qi) {
        int q = wid * 2 + qi;
        int m = nbr_cnt[q];              // m <= 32
        int b = q >> 10;
        float qx = pos[2 * q], qy = pos[2 * q + 1];
        int row = min(max((int)(qy * 32.0f), 0), 31);
        int col = min(max((int)(qx * 32.0f), 0), 31);
        int pixq = (b << 10) + row * 32 + col;
        // per-query shp (bf16 pairs), 4 uint4 = this lane's 32 features
        uint4 sv0 = *(const uint4*)&shpbuf[pixq * 64 + 0 * 16 + koff];
        uint4 sv1 = *(const uint4*)&shpbuf[pixq * 64 + 1 * 16 + koff];
        uint4 sv2 = *(const uint4*)&shpbuf[pixq * 64 + 2 * 16 + koff];
        uint4 sv3 = *(const uint4*)&shpbuf[pixq * 64 + 3 * 16 + koff];
        int nv = (lane < m) ? nbrs[q * KNB + lane] : 0;
        float om0[4], om1[4], om2[4], om3[4];
#pragma unroll
        for (int r = 0; r < 4; ++r) { om0[r] = -INFINITY; om1[r] = -INFINITY; om2[r] = -INFINITY; om3[r] = -INFINITY; }

        for (int mt = 0; mt * 16 < m; ++mt) {       // at most 2 tiles
            int src = __shfl(nv, mt * 16 + em);
            const unsigned int* wp = &wbuf[src * 64 + koff];
            floatx4 a0 = {0,0,0,0}, a1 = {0,0,0,0}, a2 = {0,0,0,0}, a3 = {0,0,0,0};
#pragma unroll
            for (int ks = 0; ks < 4; ++ks) {
                uint4 wv = *(const uint4*)&wp[ks * 16];
                uint4 sv = (ks == 0) ? sv0 : (ks == 1) ? sv1 : (ks == 2) ? sv2 : sv3;
                union { unsigned int u[4]; short8 s8; } af;
#pragma unroll
                for (int qd = 0; qd < 4; ++qd) {
                    unsigned int wd = (qd == 0) ? wv.x : (qd == 1) ? wv.y : (qd == 2) ? wv.z : wv.w;
                    unsigned int sd = (qd == 0) ? sv.x : (qd == 1) ? sv.y : (qd == 2) ? sv.z : sv.w;
                    float lo = fmaxf(bf_lo(wd) + bf_lo(sd), 0.0f);
                    float hi = fmaxf(bf_hi(wd) + bf_hi(sd), 0.0f);
                    af.u[qd] = pack_bf2(lo, hi);
                }
                a0 = __builtin_amdgcn_mfma_f32_16x16x32_bf16(af.s8, bfrag[0][ks], a0, 0, 0, 0);
                a1 = __builtin_amdgcn_mfma_f32_16x16x32_bf16(af.s8, bfrag[1][ks], a1, 0, 0, 0);
                a2 = __builtin_amdgcn_mfma_f32_16x16x32_bf16(af.s8, bfrag[2][ks], a2, 0, 0, 0);
                a3 = __builtin_amdgcn_mfma_f32_16x16x32_bf16(af.s8, bfrag[3][ks], a3, 0, 0, 0);
            }
            int rowb = (lane >> 4) * 4;
#pragma unroll
            for (int r = 0; r < 4; ++r) {
                int e = mt * 16 + rowb + r;
                if (e < m) {
                    om0[r] = fmaxf(om0[r], a0[r]);
                    om1[r] = fmaxf(om1[r], a1[r]);
                    om2[r] = fmaxf(om2[r], a2[r]);
                    om3[r] = fmaxf(om3[r], a3[r]);
                }
            }
        }
        float w0 = fmaxf(fmaxf(om0[0], om0[1]), fmaxf(om0[2], om0[3]));
        float w1 = fmaxf(fmaxf(om1[0], om1[1]), fmaxf(om1[2], om1[3]));
        float w2 = fmaxf(fmaxf(om2[0], om2[1]), fmaxf(om2[2], om2[3]));
        float w3 = fmaxf(fmaxf(om3[0], om3[1]), fmaxf(om3[2], om3[3]));
        w0 = fmaxf(w0, __shfl_xor(w0, 16)); w0 = fmaxf(w0, __shfl_xor(w0, 32));
        w1 = fmaxf(w1, __shfl_xor(w1, 16)); w1 = fmaxf(w1, __shfl_xor(w1, 32));
        w2 = fmaxf(w2, __shfl_xor(w2, 16)); w2 = fmaxf(w2, __shfl_xor(w2, 32));
        w3 = fmaxf(w3, __shfl_xor(w3, 16)); w3 = fmaxf(w3, __shfl_xor(w3, 32));
        int g4 = lane >> 4;   // feature = g4*16 + (lane&15) = lane
        float vf = (g4 == 0) ? w0 : (g4 == 1) ? w1 : (g4 == 2) ? w2 : w3;
        vf += b2l;            // m==0 -> -inf: ignored by k_gather's max
        scratch[islot[q] * 64 + lane] = vf;    // plain coalesced store, no atomics
    }
}

// ---------- gather: per pixel, max(self, contiguous query slots) ------------
__launch_bounds__(256)
__global__ void k_gather(const float* __restrict__ scratch, const float* __restrict__ selfbuf,
                         const int* __restrict__ qcnt, const int* __restrict__ qstart,
                         float* __restrict__ out) {
    int tid = threadIdx.x, wave = tid >> 6, lane = tid & 63;
    int n = blockIdx.x * 4 + wave;
    int c = qcnt[n];
    if (c == 0) return;                  // out already holds the self value
    int qs = qstart[n];
    float v = selfbuf[n * 64 + lane];
    for (int i = 0; i < c; ++i)
        v = fmaxf(v, scratch[(qs + i) * 64 + lane]);
    out[(n >> 10) * 65536 + lane * 1024 + (n & 1023)] = v;
}

extern "C" void kernel_launch(void* const* d_in, const int* in_sizes, int n_in,
                              void* d_out, int out_size, void* d_ws, size_t ws_size,
                              hipStream_t stream) {
    const float* x     = (const float*)d_in[0];
    const float* pos   = (const float*)d_in[1];
    // d_in[2] = batch (unused: points are sorted, b = idx >> 10)
    const float* W1    = (const float*)d_in[3];
    const float* b1    = (const float*)d_in[4];
    const float* gamma = (const float*)d_in[5];
    const float* beta  = (const float*)d_in[6];
    const float* W2    = (const float*)d_in[7];
    const float* b2    = (const float*)d_in[8];
    float* out = (float*)d_out;
    char* ws = (char*)d_ws;
    int*   nbrs     = (int*)(ws + WS_NBRS);
    int*   nbr_cnt  = (int*)(ws + WS_NBRCNT);
    float* deg      = (float*)(ws + WS_DEG);
    float* stx      = (float*)(ws + WS_STX);
    float* sty      = (float*)(ws + WS_STY);
    float* defrep   = (float*)(ws + WS_DEFREP);
    float* scsh     = (float*)(ws + WS_SCSH);
    unsigned short* w2b = (unsigned short*)(ws + WS_W2B);
    float* partials = (float*)(ws + WS_PART);
    unsigned int* yb = (unsigned int*)(ws + WS_Y);
    float* scratch  = (float*)(ws + WS_SCRATCH);        // overlays yb (dead after k_self)
    unsigned int* wbuf = (unsigned int*)(ws + WS_WB);
    int* qcnt   = (int*)(ws + WS_QCNT);
    int* qstart = (int*)(ws + WS_QSTART);
    int* qlist  = (int*)(ws + WS_QLIST);
    int* islot  = (int*)(ws + WS_ISLOT);
    float* selfbuf = (float*)(ws + WS_SELF);
    unsigned int* shpbuf = (unsigned int*)(ws + WS_SHP);
    float* bqpart   = (float*)(ws + WS_BQPART);         // overlays self+shp (dead before k_self)

    k_prep<<<32, 256, 0, stream>>>(W2, w2b, defrep, pos, qcnt, qstart, qlist, islot);
    k_ballquery<<<1024, 256, 0, stream>>>(pos, nbrs, nbr_cnt, bqpart, defrep);
    k_nodeagg<<<128, 256, 0, stream>>>(bqpart, deg, stx, sty);
    k_y<<<256, 256, 0, stream>>>(x, W1, b1, pos, deg, stx, sty, yb, partials);
    k_finalize<<<1, 256, 0, stream>>>(gamma, beta, W1, partials, defrep, scsh);
    k_self<<<NPTS / 64, 256, 0, stream>>>(yb, pos, W1, scsh, w2b, b2, wbuf, shpbuf, selfbuf, out);
    k_out<<<NPTS / 8, 256, 0, stream>>>(wbuf, shpbuf, pos, w2b, b2,
                                        nbrs, nbr_cnt, islot, scratch);
    k_gather<<<NPTS / 4, 256, 0, stream>>>(scratch, selfbuf, qcnt, qstart, out);
}

// Round 11
// 247.184 us; speedup vs baseline: 1.6282x; 1.0091x over previous
//
#include <hip/hip_runtime.h>
#include <hip/hip_bf16.h>
#include <hip/hip_fp16.h>
#include <math.h>

// ---------------------------------------------------------------------------
// PointsToImage: ball-query (K=32, R=0.1) -> PointNetConv msg=[x_j, pos_j-pos_dst]
// -> Linear(66,128) -> masked-BatchNorm -> ReLU -> Linear(128,64) -> scatter-max
// into pixel nodes, output [B=32, F=64, 32, 32] fp32.
//
// R11 (= R10 with compile fix): GEMM2 fp16. k_out edge math = 2 packed-half
// VALU ops per dword via native _Float16 ext-vectors (v_pk_add_f16 +
// v_pk_max_f16) -- NOT __hadd2/__hmax2 (ambiguous with hip_bf16.h overloads
// on ROCm 7.2). wbuf/shpbuf/w2b fp16; MFMA = mfma_f32_16x16x32_f16.
// Pipeline: k_prep(pixmap+pack) -> k_ballquery -> k_nodeagg -> k_y ->
//           k_finalize -> k_self -> k_out -> k_gather
// ---------------------------------------------------------------------------

#define NPTS   32768
#define KNB    32
#define BN_EPS 1e-5f

// workspace layout (bytes)
#define WS_NBRS     0u           // int[NPTS*KNB]      = 4194304
#define WS_NBRCNT   4194304u     // int[NPTS]          = 131072
#define WS_DEG      4325376u     // float[NPTS]        = 131072
#define WS_STX      4456448u     // float[NPTS]        = 131072
#define WS_STY      4587520u     // float[NPTS]        = 131072
#define WS_DEFREP   4718592u     // float[64*4]        = 1024
#define WS_SCSH     4719616u     // float[256]         = 1024
#define WS_W2B      4720640u     // ushort[8192]       = 16384 (W2 B-frag, fp16)
#define WS_PART     4737024u     // float[256*516]     = 528384
#define WS_Y        5265408u     // uint[NPTS*64]      = 8388608 (yb; dead after k_self)
#define WS_SCRATCH  5265408u     // float[NPTS*64]     = 8388608 (OVERLAYS yb)
#define WS_WB       13654016u    // uint[NPTS*64]      = 8388608 (w, fp16 pairs)
#define WS_QCNT     22042624u    // int[NPTS]          = 131072
#define WS_QSTART   22173696u    // int[NPTS]          = 131072
#define WS_QLIST    22304768u    // int[NPTS]          = 131072
#define WS_ISLOT    22435840u    // int[NPTS]          = 131072
#define WS_SELF     22566912u    // float[NPTS*64]     = 8388608
#define WS_SHP      30955520u    // uint[NPTS*64]      = 8388608 (shp, fp16 pairs)
#define WS_BQPART   22566912u    // float[1024*3072]   = 12582912 (OVERLAYS self+shp;
                                 //   dead after k_nodeagg, before k_self writes them)

typedef __attribute__((ext_vector_type(8))) _Float16 half8;
typedef __attribute__((ext_vector_type(2))) _Float16 half2v;
typedef __attribute__((ext_vector_type(4))) float floatx4;

__device__ __forceinline__ unsigned short f2h_bits(float f) {
    _Float16 h = (_Float16)f;
    return *reinterpret_cast<unsigned short*>(&h);
}
__device__ __forceinline__ float bf_lo(unsigned int w) { return __uint_as_float(w << 16); }
__device__ __forceinline__ float bf_hi(unsigned int w) { return __uint_as_float(w & 0xffff0000u); }
__device__ __forceinline__ unsigned int pack_bf2(float lo, float hi) {
    __hip_bfloat162 hh = __float22bfloat162_rn(make_float2(lo, hi));
    return *reinterpret_cast<unsigned int*>(&hh);
}
__device__ __forceinline__ unsigned int pack_h2(float lo, float hi) {
    half2v hh = { (_Float16)lo, (_Float16)hi };
    return *reinterpret_cast<unsigned int*>(&hh);
}

// ---------- prep: W2 B-frag pack (fp16) + defrep zero + query->pixel map ----
__launch_bounds__(256)
__global__ void k_prep(const float* __restrict__ W2, unsigned short* __restrict__ w2b,
                       float* __restrict__ defrep, const float* __restrict__ pos,
                       int* __restrict__ qcnt, int* __restrict__ qstart,
                       int* __restrict__ qlist, int* __restrict__ islot) {
    int tid = threadIdx.x;
    int gt = blockIdx.x * 256 + tid;          // 32 blocks * 256 = 8192
    if (gt < 256) defrep[gt] = 0.0f;
    {   // W2 pack: B-frag lane L holds B[k=(L>>4)*8+j][n=L&15]
        int j  = gt & 7;
        int L  = (gt >> 3) & 63;
        int ks = (gt >> 9) & 3;
        int t4 = gt >> 11;
        int k = ks * 32 + (L >> 4) * 8 + j;
        int n = t4 * 16 + (L & 15);
        w2b[gt] = f2h_bits(W2[k * 64 + n]);
    }
    // pixel map for sample s = blockIdx.x
    __shared__ int cntS[1024], preS[1024], offS[1024], pixOf[1024];
    __shared__ int wtot[4];
    int s = blockIdx.x;
    int base = s << 10;
    for (int i = tid; i < 1024; i += 256) cntS[i] = 0;
    __syncthreads();
    for (int ql = tid; ql < 1024; ql += 256) {
        float2 p = *(const float2*)&pos[2 * (base + ql)];
        int row = min(max((int)(p.y * 32.0f), 0), 31);
        int col = min(max((int)(p.x * 32.0f), 0), 31);
        int pixl = row * 32 + col;
        pixOf[ql] = pixl;
        atomicAdd(&cntS[pixl], 1);
    }
    __syncthreads();
    int a0 = cntS[4 * tid], a1 = cntS[4 * tid + 1], a2 = cntS[4 * tid + 2], a3 = cntS[4 * tid + 3];
    int tsum = a0 + a1 + a2 + a3;
    int lane = tid & 63, wv = tid >> 6;
    int v = tsum;
    for (int o = 1; o < 64; o <<= 1) { int u = __shfl_up(v, o); if (lane >= o) v += u; }
    if (lane == 63) wtot[wv] = v;
    __syncthreads();
    int wbase = 0;
    for (int w = 0; w < wv; ++w) wbase += wtot[w];
    int excl = wbase + v - tsum;
    preS[4 * tid] = excl;
    preS[4 * tid + 1] = excl + a0;
    preS[4 * tid + 2] = excl + a0 + a1;
    preS[4 * tid + 3] = excl + a0 + a1 + a2;
    __syncthreads();
    for (int i = tid; i < 1024; i += 256) offS[i] = preS[i];
    __syncthreads();
    for (int ql = tid; ql < 1024; ql += 256) {
        int p = pixOf[ql];
        int slot = atomicAdd(&offS[p], 1);
        qlist[base + slot] = base + ql;
        islot[base + ql] = base + slot;
    }
    for (int i = tid; i < 1024; i += 256) {
        qcnt[base + i] = cntS[i];
        qstart[base + i] = base + preS[i];
    }
}

// ------------- ball query: ballot-prefix compaction, zero counter atomics ---
__launch_bounds__(256)
__global__ void k_ballquery(const float* __restrict__ pos,
                            int* __restrict__ nbrs, int* __restrict__ nbr_cnt,
                            float* __restrict__ bqpart, float* __restrict__ defrep) {
    __shared__ float2 poss[1024];
    __shared__ float accd[1024], accx[1024], accy[1024];
    __shared__ unsigned long long cand[4][256];
    int tid = threadIdx.x, wave = tid >> 6, lane = tid & 63;
    int s = blockIdx.x >> 5;           // sample
    int chunk = blockIdx.x & 31;       // 32 chunks of 32 queries
    int base = s << 10;
    for (int i = tid; i < 1024; i += 256) poss[i] = *(const float2*)&pos[2 * (base + i)];
    for (int i = tid; i < 1024; i += 256) { accd[i] = 0.0f; accx[i] = 0.0f; accy[i] = 0.0f; }
    __syncthreads();
    float2 pr[16];
#pragma unroll
    for (int k = 0; k < 16; ++k) pr[k] = poss[k * 64 + lane];
    unsigned long long lb = (1ull << lane) - 1ull;   // bits below this lane

    float aD = 0, aE = 0, aF = 0;
    for (int qi = 0; qi < 8; ++qi) {
        int ql = chunk * 32 + wave * 8 + qi;
        int q = base + ql;
        float2 qp = poss[ql];
        int row = min(max((int)(qp.y * 32.0f), 0), 31);
        int col = min(max((int)(qp.x * 32.0f), 0), 31);
        int pixl = row * 32 + col;
        float2 tp = poss[pixl];
        int cnt = 0;
        __builtin_amdgcn_wave_barrier();
#pragma unroll
        for (int k = 0; k < 16; ++k) {
            float dx = pr[k].x - qp.x, dy = pr[k].y - qp.y;
            float d2 = __fadd_rn(__fmul_rn(dx, dx), __fmul_rn(dy, dy)); // no FMA contraction
            bool pred = (d2 <= 0.01f);
            unsigned long long mask = __ballot(pred);
            if (pred) {
                int slot = cnt + (int)__popcll(mask & lb);
                if (slot < 256)
                    cand[wave][slot] = ((unsigned long long)__float_as_uint(d2) << 32)
                                       | (unsigned int)(k * 64 + lane);
            }
            cnt += (int)__popcll(mask);
        }
        cnt = min(cnt, 256);
        __builtin_amdgcn_wave_barrier();
        int osel = 0;
        for (int cb = 0; cb < cnt; cb += 64) {
            int i = cb + lane;
            bool sel = false;
            int j = 0;
            if (i < cnt) {
                unsigned long long key = cand[wave][i];
                j = (int)(key & 0xffffffffu);
                if (cnt <= KNB) {
                    sel = (j != pixl);                 // all in-radius are top-K
                } else {
                    int rank = 0;
                    for (int t = 0; t < cnt; ++t) rank += (cand[wave][t] < key) ? 1 : 0;
                    sel = (rank < KNB) && (j != pixl); // top-K, then remove_self_loops
                }
            }
            unsigned long long mask = __ballot(sel);
            if (sel) {
                int slot = osel + (int)__popcll(mask & lb);
                nbrs[q * KNB + slot] = base + j;
                float rx = poss[j].x - tp.x, ry = poss[j].y - tp.y;
                aD += rx * rx; aE += rx * ry; aF += ry * ry;
                atomicAdd(&accd[j], 1.0f);
                atomicAdd(&accx[j], tp.x);
                atomicAdd(&accy[j], tp.y);
            }
            osel += (int)__popcll(mask);
        }
        if (lane == 0) nbr_cnt[q] = osel;
    }
#pragma unroll
    for (int o = 1; o < 64; o <<= 1) {
        aD += __shfl_xor(aD, o); aE += __shfl_xor(aE, o); aF += __shfl_xor(aF, o);
    }
    __syncthreads();
    float* pb = &bqpart[blockIdx.x * 3072];
    for (int i = tid; i < 1024; i += 256) {
        pb[i] = accd[i]; pb[1024 + i] = accx[i]; pb[2048 + i] = accy[i];
    }
    if (tid == 0) {
        int r = (blockIdx.x & 63) * 4;
        atomicAdd(&defrep[r + 0], aD);
        atomicAdd(&defrep[r + 1], aE);
        atomicAdd(&defrep[r + 2], aF);
    }
}

// ------------------- sum the 32 chunk partials per node ---------------------
__global__ void k_nodeagg(const float* __restrict__ bqpart, float* __restrict__ deg,
                          float* __restrict__ stx, float* __restrict__ sty) {
    int t = blockIdx.x * 256 + threadIdx.x;   // 128 blocks -> 32768
    int s = t >> 10, off = t & 1023;
    const float* pb = &bqpart[(s * 32) * 3072];
    float d = 0, xx = 0, yy = 0;
    for (int j = 0; j < 32; ++j) {
        d  += pb[j * 3072 + off];
        xx += pb[j * 3072 + 1024 + off];
        yy += pb[j * 3072 + 2048 + off];
    }
    deg[t] = d; stx[t] = xx; sty[t] = yy;
}

// ---------------- node GEMM1 + folded BN node-stats: y = x@W1[:64]+b1 -------
// lane owns features f0=2*lane, f1=2*lane+1. yb packed bf16 (f0 lo, f1 hi).
__launch_bounds__(256)
__global__ void k_y(const float* __restrict__ x, const float* __restrict__ W1,
                    const float* __restrict__ b1, const float* __restrict__ pos,
                    const float* __restrict__ deg, const float* __restrict__ stxA,
                    const float* __restrict__ styA,
                    unsigned int* __restrict__ yb, float* __restrict__ partials) {
    __shared__ float w1s[64 * 128];
    __shared__ float stage[4][512];
    __shared__ float lsum[515];
    int tid = threadIdx.x;
    for (int i = tid; i < 64 * 128; i += 256) w1s[i] = W1[i];
    for (int i = tid; i < 515; i += 256) lsum[i] = 0.0f;
    __syncthreads();
    int wave = tid >> 6, lane = tid & 63;
    int f0 = 2 * lane, f1 = 2 * lane + 1;
    float b10 = b1[f0], b11 = b1[f1];
    float* st = &stage[wave][0];
    float P0 = 0, Q0 = 0, R0 = 0, S0 = 0, P1 = 0, Q1 = 0, R1 = 0, S1 = 0;
    float sB = 0, sC = 0, sDeg = 0;

    for (int it = 0; it < 4; ++it) {
        int nbase = ((blockIdx.x * 4 + wave) * 4 + it) * 8;
        __builtin_amdgcn_wave_barrier();
#pragma unroll
        for (int mm = 0; mm < 8; ++mm)
            st[mm * 64 + lane] = x[(nbase + mm) * 64 + lane];
        __builtin_amdgcn_wave_barrier();
        float z0[8], z1[8];
#pragma unroll
        for (int mm = 0; mm < 8; ++mm) { z0[mm] = b10; z1[mm] = b11; }
        for (int k4 = 0; k4 < 16; ++k4) {
            float2 wv0 = *(const float2*)&w1s[(k4 * 4 + 0) * 128 + f0];
            float2 wv1 = *(const float2*)&w1s[(k4 * 4 + 1) * 128 + f0];
            float2 wv2 = *(const float2*)&w1s[(k4 * 4 + 2) * 128 + f0];
            float2 wv3 = *(const float2*)&w1s[(k4 * 4 + 3) * 128 + f0];
#pragma unroll
            for (int mm = 0; mm < 8; ++mm) {
                float4 mk = *(const float4*)&st[mm * 64 + k4 * 4];
                z0[mm] += mk.x * wv0.x + mk.y * wv1.x + mk.z * wv2.x + mk.w * wv3.x;
                z1[mm] += mk.x * wv0.y + mk.y * wv1.y + mk.z * wv2.y + mk.w * wv3.y;
            }
        }
#pragma unroll
        for (int mm = 0; mm < 8; ++mm) {
            int n = nbase + mm;
            float dg = deg[n];
            float wgt = 1.0f + dg;
            float Bn = dg * pos[2 * n]     - stxA[n];
            float Cn = dg * pos[2 * n + 1] - styA[n];
            float a = z0[mm], bq = z1[mm];
            P0 += wgt * a;  Q0 += wgt * a * a;  R0 += a * Bn;  S0 += a * Cn;
            P1 += wgt * bq; Q1 += wgt * bq * bq; R1 += bq * Bn; S1 += bq * Cn;
            sB += Bn; sC += Cn; sDeg += dg;
            yb[n * 64 + lane] = pack_bf2(a, bq);
        }
    }
    atomicAdd(&lsum[f0], P0);        atomicAdd(&lsum[f1], P1);
    atomicAdd(&lsum[128 + f0], Q0);  atomicAdd(&lsum[128 + f1], Q1);
    atomicAdd(&lsum[256 + f0], R0);  atomicAdd(&lsum[256 + f1], R1);
    atomicAdd(&lsum[384 + f0], S0);  atomicAdd(&lsum[384 + f1], S1);
    if (lane == 0) {
        atomicAdd(&lsum[512], sB);
        atomicAdd(&lsum[513], sC);
        atomicAdd(&lsum[514], sDeg);
    }
    __syncthreads();
    for (int i = tid; i < 515; i += 256) partials[blockIdx.x * 516 + i] = lsum[i];
}

// --------------------------- finalize BN scale/shift ------------------------
__global__ void k_finalize(const float* __restrict__ gamma, const float* __restrict__ beta,
                           const float* __restrict__ W1, const float* __restrict__ partials,
                           const float* __restrict__ defrep, float* __restrict__ scsh) {
    __shared__ float red[515];
    __shared__ float sDEF[3];
    int tid = threadIdx.x;    // 256
    for (int i = tid; i < 515; i += 256) {
        float s = 0;
        for (int b = 0; b < 256; ++b) s += partials[b * 516 + i];
        red[i] = s;
    }
    if (tid < 3) {
        float s = 0;
        for (int r = 0; r < 64; ++r) s += defrep[r * 4 + tid];
        sDEF[tid] = s;
    }
    __syncthreads();
    if (tid < 128) {
        int f = tid;
        float P = red[f], Q = red[128 + f], R = red[256 + f], S = red[384 + f];
        float SB = red[512], SC = red[513], SDeg = red[514];
        float u = W1[8192 + f], v = W1[8320 + f];
        float cntv = 32768.0f + SDeg;
        float mean = (P + u * SB + v * SC) / cntv;
        float E2 = (Q + 2.0f * u * R + 2.0f * v * S
                    + u * u * sDEF[0] + 2.0f * u * v * sDEF[1] + v * v * sDEF[2]) / cntv;
        float var = E2 - mean * mean;
        float sc = gamma[f] / sqrtf(var + BN_EPS);
        scsh[f] = sc;
        scsh[128 + f] = beta[f] - mean * sc;
    }
}

// ---------- self pass (MFMA f16) + w/shp precompute (fp16) ------------------
__launch_bounds__(256)
__global__ void k_self(const unsigned int* __restrict__ yb, const float* __restrict__ pos,
                       const float* __restrict__ W1, const float* __restrict__ scsh,
                       const unsigned short* __restrict__ w2b, const float* __restrict__ b2,
                       const int* __restrict__ qcnt,
                       unsigned int* __restrict__ wbuf, unsigned int* __restrict__ shpbuf,
                       float* __restrict__ selfbuf, float* __restrict__ out) {
    __shared__ unsigned short hbuf[4][16 * 136];   // 272 B row stride
    int tid = threadIdx.x, wave = tid >> 6, lane = tid & 63;
    unsigned short* hb = hbuf[wave];
    half8 bfrag[4][4];
#pragma unroll
    for (int t = 0; t < 4; ++t)
#pragma unroll
        for (int ks = 0; ks < 4; ++ks)
            bfrag[t][ks] = *(const half8*)&w2b[((t * 4 + ks) * 64 + lane) * 8];
    int f0 = 2 * lane;
    float sc0 = scsh[f0],     sh0 = scsh[128 + f0];
    float sc1 = scsh[f0 + 1], sh1 = scsh[129 + f0];
    float u0 = W1[8192 + f0], v0 = W1[8320 + f0];
    float u1 = W1[8193 + f0], v1 = W1[8321 + f0];
    float b2v0 = b2[(lane & 15)],      b2v1 = b2[16 + (lane & 15)];
    float b2v2 = b2[32 + (lane & 15)], b2v3 = b2[48 + (lane & 15)];

    int nbase = (blockIdx.x * 4 + wave) * 16;
#pragma unroll
    for (int c = 0; c < 2; ++c) {
        unsigned int yw[8];
#pragma unroll
        for (int j = 0; j < 8; ++j)
            yw[j] = yb[(nbase + c * 8 + j) * 64 + lane];
#pragma unroll
        for (int j = 0; j < 8; ++j) {
            int e = c * 8 + j;
            int nn = nbase + e;
            float y0 = bf_lo(yw[j]), y1 = bf_hi(yw[j]);
            float h0 = fmaxf(y0 * sc0 + sh0, 0.0f);
            float h1 = fmaxf(y1 * sc1 + sh1, 0.0f);
            *(unsigned int*)&hb[e * 136 + f0] = pack_h2(h0, h1);
            float px = pos[2 * nn], py = pos[2 * nn + 1];
            float ts0 = (px * u0 + py * v0) * sc0;
            float ts1 = (px * u1 + py * v1) * sc1;
            wbuf[nn * 64 + lane]   = pack_h2(y0 * sc0 + ts0, y1 * sc1 + ts1);
            shpbuf[nn * 64 + lane] = pack_h2(sh0 - ts0, sh1 - ts1);
        }
    }
    __builtin_amdgcn_wave_barrier();
    floatx4 acc0 = {0,0,0,0}, acc1 = {0,0,0,0}, acc2 = {0,0,0,0}, acc3 = {0,0,0,0};
#pragma unroll
    for (int ks = 0; ks < 4; ++ks) {
        half8 a = *(const half8*)&hb[(lane & 15) * 136 + ks * 32 + (lane >> 4) * 8];
        acc0 = __builtin_amdgcn_mfma_f32_16x16x32_f16(a, bfrag[0][ks], acc0, 0, 0, 0);
        acc1 = __builtin_amdgcn_mfma_f32_16x16x32_f16(a, bfrag[1][ks], acc1, 0, 0, 0);
        acc2 = __builtin_amdgcn_mfma_f32_16x16x32_f16(a, bfrag[2][ks], acc2, 0, 0, 0);
        acc3 = __builtin_amdgcn_mfma_f32_16x16x32_f16(a, bfrag[3][ks], acc3, 0, 0, 0);
    }
    int nrow = nbase + (lane >> 4) * 4;
#pragma unroll
    for (int r = 0; r < 4; ++r) {
        int n = nrow + r;
        float o0 = acc0[r] + b2v0, o1 = acc1[r] + b2v1;
        float o2 = acc2[r] + b2v2, o3 = acc3[r] + b2v3;
        selfbuf[n * 64 + (lane & 15)]      = o0;   // contiguous copy for k_gather
        selfbuf[n * 64 + 16 + (lane & 15)] = o1;
        selfbuf[n * 64 + 32 + (lane & 15)] = o2;
        selfbuf[n * 64 + 48 + (lane & 15)] = o3;
        if (qcnt[n] == 0) {                 // k_gather overwrites qcnt>0 nodes
            int obase = (n >> 10) * 65536 + (n & 1023);
            out[obase + ((lane & 15)) * 1024]      = o0;
            out[obase + (16 + (lane & 15)) * 1024] = o1;
            out[obase + (32 + (lane & 15)) * 1024] = o2;
            out[obase + (48 + (lane & 15)) * 1024] = o3;
        }
    }
}

// ---------- neighbor pass: LDS-free, fp16 packed edge math ------------------
__launch_bounds__(256)
__global__ void k_out(const unsigned int* __restrict__ wbuf,
                      const unsigned int* __restrict__ shpbuf,
                      const float* __restrict__ pos,
                      const unsigned short* __restrict__ w2b, const float* __restrict__ b2,
                      const int* __restrict__ nbrs, const int* __restrict__ nbr_cnt,
                      const int* __restrict__ islot, float* __restrict__ scratch) {
    int tid = threadIdx.x, wave = tid >> 6, lane = tid & 63;
    half8 bfrag[4][4];
#pragma unroll
    for (int t = 0; t < 4; ++t)
#pragma unroll
        for (int ks = 0; ks < 4; ++ks)
            bfrag[t][ks] = *(const half8*)&w2b[((t * 4 + ks) * 64 + lane) * 8];
    float b2l = b2[lane];
    int em = lane & 15;                  // edge-in-tile this lane's A-frag covers
    int koff = (lane >> 4) * 4;          // dword offset of this lane's 8 features
    int wid = blockIdx.x * 4 + wave;     // 16384 waves, 2 queries each

    for (int qi = 0; qi < 2; ++qi) {
        int q = wid * 2 + qi;
        int m = nbr_cnt[q];              // m <= 32
        int b = q >> 10;
        float qx = pos[2 * q], qy = pos[2 * q + 1];
        int row = min(max((int)(qy * 32.0f), 0), 31);
        int col = min(max((int)(qx * 32.0f), 0), 31);
        int pixq = (b << 10) + row * 32 + col;
        // per-query shp (fp16 pairs), 4 uint4 = this lane's 32 features
        uint4 sv0 = *(const uint4*)&shpbuf[pixq * 64 + 0 * 16 + koff];
        uint4 sv1 = *(const uint4*)&shpbuf[pixq * 64 + 1 * 16 + koff];
        uint4 sv2 = *(const uint4*)&shpbuf[pixq * 64 + 2 * 16 + koff];
        uint4 sv3 = *(const uint4*)&shpbuf[pixq * 64 + 3 * 16 + koff];
        int nv = (lane < m) ? nbrs[q * KNB + lane] : 0;
        float om0[4], om1[4], om2[4], om3[4];
#pragma unroll
        for (int r = 0; r < 4; ++r) { om0[r] = -INFINITY; om1[r] = -INFINITY; om2[r] = -INFINITY; om3[r] = -INFINITY; }

        for (int mt = 0; mt * 16 < m; ++mt) {       // at most 2 tiles
            int src = __shfl(nv, mt * 16 + em);
            const unsigned int* wp = &wbuf[src * 64 + koff];
            floatx4 a0 = {0,0,0,0}, a1 = {0,0,0,0}, a2 = {0,0,0,0}, a3 = {0,0,0,0};
#pragma unroll
            for (int ks = 0; ks < 4; ++ks) {
                uint4 wv = *(const uint4*)&wp[ks * 16];
                uint4 sv = (ks == 0) ? sv0 : (ks == 1) ? sv1 : (ks == 2) ? sv2 : sv3;
                union { unsigned int u[4]; half8 h8; } af;
#pragma unroll
                for (int qd = 0; qd < 4; ++qd) {
                    unsigned int wd = (qd == 0) ? wv.x : (qd == 1) ? wv.y : (qd == 2) ? wv.z : wv.w;
                    unsigned int sd = (qd == 0) ? sv.x : (qd == 1) ? sv.y : (qd == 2) ? sv.z : sv.w;
                    half2v wh = *reinterpret_cast<half2v*>(&wd);
                    half2v sh = *reinterpret_cast<half2v*>(&sd);
                    half2v zz = { (_Float16)0.0f, (_Float16)0.0f };
                    half2v hh = __builtin_elementwise_max(wh + sh, zz);  // v_pk_add + v_pk_max
                    af.u[qd] = *reinterpret_cast<unsigned int*>(&hh);
                }
                a0 = __builtin_amdgcn_mfma_f32_16x16x32_f16(af.h8, bfrag[0][ks], a0, 0, 0, 0);
                a1 = __builtin_amdgcn_mfma_f32_16x16x32_f16(af.h8, bfrag[1][ks], a1, 0, 0, 0);
                a2 = __builtin_amdgcn_mfma_f32_16x16x32_f16(af.h8, bfrag[2][ks], a2, 0, 0, 0);
                a3 = __builtin_amdgcn_mfma_f32_16x16x32_f16(af.h8, bfrag[3][ks], a3, 0, 0, 0);
            }
            int rowb = (lane >> 4) * 4;
#pragma unroll
            for (int r = 0; r < 4; ++r) {
                int e = mt * 16 + rowb + r;
                if (e < m) {
                    om0[r] = fmaxf(om0[r], a0[r]);
                    om1[r] = fmaxf(om1[r], a1[r]);
                    om2[r] = fmaxf(om2[r], a2[r]);
                    om3[r] = fmaxf(om3[r], a3[r]);
                }
            }
        }
        float w0 = fmaxf(fmaxf(om0[0], om0[1]), fmaxf(om0[2], om0[3]));
        float w1 = fmaxf(fmaxf(om1[0], om1[1]), fmaxf(om1[2], om1[3]));
        float w2 = fmaxf(fmaxf(om2[0], om2[1]), fmaxf(om2[2], om2[3]));
        float w3 = fmaxf(fmaxf(om3[0], om3[1]), fmaxf(om3[2], om3[3]));
        w0 = fmaxf(w0, __shfl_xor(w0, 16)); w0 = fmaxf(w0, __shfl_xor(w0, 32));
        w1 = fmaxf(w1, __shfl_xor(w1, 16)); w1 = fmaxf(w1, __shfl_xor(w1, 32));
        w2 = fmaxf(w2, __shfl_xor(w2, 16)); w2 = fmaxf(w2, __shfl_xor(w2, 32));
        w3 = fmaxf(w3, __shfl_xor(w3, 16)); w3 = fmaxf(w3, __shfl_xor(w3, 32));
        int g4 = lane >> 4;   // feature = g4*16 + (lane&15) = lane
        float vf = (g4 == 0) ? w0 : (g4 == 1) ? w1 : (g4 == 2) ? w2 : w3;
        vf += b2l;            // m==0 -> -inf: ignored by k_gather's max
        scratch[islot[q] * 64 + lane] = vf;    // plain coalesced store, no atomics
    }
}

// ---------- gather: per pixel, max(self, contiguous query slots) ------------
__launch_bounds__(256)
__global__ void k_gather(const float* __restrict__ scratch, const float* __restrict__ selfbuf,
                         const int* __restrict__ qcnt, const int* __restrict__ qstart,
                         float* __restrict__ out) {
    int tid = threadIdx.x, wave = tid >> 6, lane = tid & 63;
    int n = blockIdx.x * 4 + wave;
    int c = qcnt[n];
    if (c == 0) return;                  // out written by k_self
    int qs = qstart[n];
    float v = selfbuf[n * 64 + lane];
    for (int i = 0; i < c; ++i)
        v = fmaxf(v, scratch[(qs + i) * 64 + lane]);
    out[(n >> 10) * 65536 + lane * 1024 + (n & 1023)] = v;
}

extern "C" void kernel_launch(void* const* d_in, const int* in_sizes, int n_in,
                              void* d_out, int out_size, void* d_ws, size_t ws_size,
                              hipStream_t stream) {
    const float* x     = (const float*)d_in[0];
    const float* pos   = (const float*)d_in[1];
    // d_in[2] = batch (unused: points are sorted, b = idx >> 10)
    const float* W1    = (const float*)d_in[3];
    const float* b1    = (const float*)d_in[4];
    const float* gamma = (const float*)d_in[5];
    const float* beta  = (const float*)d_in[6];
    const float* W2    = (const float*)d_in[7];
    const float* b2    = (const float*)d_in[8];
    float* out = (float*)d_out;
    char* ws = (char*)d_ws;
    int*   nbrs     = (int*)(ws + WS_NBRS);
    int*   nbr_cnt  = (int*)(ws + WS_NBRCNT);
    float* deg      = (float*)(ws + WS_DEG);
    float* stx      = (float*)(ws + WS_STX);
    float* sty      = (float*)(ws + WS_STY);
    float* defrep   = (float*)(ws + WS_DEFREP);
    float* scsh     = (float*)(ws + WS_SCSH);
    unsigned short* w2b = (unsigned short*)(ws + WS_W2B);
    float* partials = (float*)(ws + WS_PART);
    unsigned int* yb = (unsigned int*)(ws + WS_Y);
    float* scratch  = (float*)(ws + WS_SCRATCH);        // overlays yb (dead after k_self)
    unsigned int* wbuf = (unsigned int*)(ws + WS_WB);
    int* qcnt   = (int*)(ws + WS_QCNT);
    int* qstart = (int*)(ws + WS_QSTART);
    int* qlist  = (int*)(ws + WS_QLIST);
    int* islot  = (int*)(ws + WS_ISLOT);
    float* selfbuf = (float*)(ws + WS_SELF);
    unsigned int* shpbuf = (unsigned int*)(ws + WS_SHP);
    float* bqpart   = (float*)(ws + WS_BQPART);         // overlays self+shp (dead before k_self)

    k_prep<<<32, 256, 0, stream>>>(W2, w2b, defrep, pos, qcnt, qstart, qlist, islot);
    k_ballquery<<<1024, 256, 0, stream>>>(pos, nbrs, nbr_cnt, bqpart, defrep);
    k_nodeagg<<<128, 256, 0, stream>>>(bqpart, deg, stx, sty);
    k_y<<<256, 256, 0, stream>>>(x, W1, b1, pos, deg, stx, sty, yb, partials);
    k_finalize<<<1, 256, 0, stream>>>(gamma, beta, W1, partials, defrep, scsh);
    k_self<<<NPTS / 64, 256, 0, stream>>>(yb, pos, W1, scsh, w2b, b2, qcnt,
                                          wbuf, shpbuf, selfbuf, out);
    k_out<<<NPTS / 8, 256, 0, stream>>>(wbuf, shpbuf, pos, w2b, b2,
                                        nbrs, nbr_cnt, islot, scratch);
    k_gather<<<NPTS / 4, 256, 0, stream>>>(scratch, selfbuf, qcnt, qstart, out);
}

// Round 12
// 246.018 us; speedup vs baseline: 1.6360x; 1.0047x over previous
//
#include <hip/hip_runtime.h>
#include <hip/hip_bf16.h>
#include <hip/hip_fp16.h>
#include <math.h>

// ---------------------------------------------------------------------------
// PointsToImage: ball-query (K=32, R=0.1) -> PointNetConv msg=[x_j, pos_j-pos_dst]
// -> Linear(66,128) -> masked-BatchNorm -> ReLU -> Linear(128,64) -> scatter-max
// into pixel nodes, output [B=32, F=64, 32, 32] fp32.
//
// R12: launch-count and latency pass.
//  - k_prep fused into k_bq (blocks 0-31 = pixmap+W2pack, 32-1055 = ballquery);
//    defrep replaced by per-block tails in bqpart (stride 3076), summed in
//    k_finalize -- no cross-block zero-init ordering needed.
//  - k_nodeagg fused into k_y (LDS pre-phase); k_y 512 threads (8 waves/CU).
//  - k_out: both tiles' gathers (8 dwordx4) issued before any MFMA; acc regs
//    reused across tiles (one exposed gather-latency per query instead of two).
// Pipeline (6 launches): k_bq -> k_y -> k_finalize -> k_self -> k_out -> k_gather
// ---------------------------------------------------------------------------

#define NPTS   32768
#define KNB    32
#define BN_EPS 1e-5f

// workspace layout (bytes) -- same envelope as R11 (max 39,344,128)
#define WS_NBRS     0u           // int[NPTS*KNB]      = 4194304
#define WS_NBRCNT   4194304u     // int[NPTS]          = 131072
#define WS_SCSH     4719616u     // float[256]
#define WS_W2B      4720640u     // ushort[8192]       (W2 B-frag, fp16)
#define WS_PART     4737024u     // float[256*516]     = 528384
#define WS_Y        5265408u     // uint[NPTS*64]      = 8388608 (yb; dead after k_self)
#define WS_SCRATCH  5265408u     // float[NPTS*64]     (OVERLAYS yb)
#define WS_WB       13654016u    // uint[NPTS*64]      = 8388608 (w, fp16 pairs)
#define WS_QCNT     22042624u    // int[NPTS]
#define WS_QSTART   22173696u    // int[NPTS]
#define WS_QLIST    22304768u    // int[NPTS]
#define WS_ISLOT    22435840u    // int[NPTS]
#define WS_SELF     22566912u    // float[NPTS*64]     = 8388608
#define WS_SHP      30955520u    // uint[NPTS*64]      = 8388608 (shp, fp16 pairs)
#define WS_BQPART   22566912u    // float[1024*3076]   = 12599296 (OVERLAYS self+shp;
                                 //   dead after k_finalize, before k_self writes)

typedef __attribute__((ext_vector_type(8))) _Float16 half8;
typedef __attribute__((ext_vector_type(2))) _Float16 half2v;
typedef __attribute__((ext_vector_type(4))) float floatx4;

__device__ __forceinline__ unsigned short f2h_bits(float f) {
    _Float16 h = (_Float16)f;
    return *reinterpret_cast<unsigned short*>(&h);
}
__device__ __forceinline__ float bf_lo(unsigned int w) { return __uint_as_float(w << 16); }
__device__ __forceinline__ float bf_hi(unsigned int w) { return __uint_as_float(w & 0xffff0000u); }
__device__ __forceinline__ unsigned int pack_bf2(float lo, float hi) {
    __hip_bfloat162 hh = __float22bfloat162_rn(make_float2(lo, hi));
    return *reinterpret_cast<unsigned int*>(&hh);
}
__device__ __forceinline__ unsigned int pack_h2(float lo, float hi) {
    half2v hh = { (_Float16)lo, (_Float16)hi };
    return *reinterpret_cast<unsigned int*>(&hh);
}

// ------------- fused prep + ball query (1056 blocks) ------------------------
// blocks 0-31:   sample pixmap inversion + W2 B-frag fp16 pack
// blocks 32-1055: ballot-prefix ball query (32 samples x 32 chunks x 32 queries)
union ShBQ {
    struct {
        float2 poss[1024];
        float accd[1024], accx[1024], accy[1024];
        unsigned long long cand[4][256];
    } bq;                                             // 28672 B
    struct {
        int cntS[1024], preS[1024], offS[1024], pixOf[1024];
        int wtot[4];
    } pm;                                             // 16400 B
};

__launch_bounds__(256)
__global__ void k_bq(const float* __restrict__ pos,
                     int* __restrict__ nbrs, int* __restrict__ nbr_cnt,
                     float* __restrict__ bqpart,
                     const float* __restrict__ W2, unsigned short* __restrict__ w2b,
                     int* __restrict__ qcnt, int* __restrict__ qstart,
                     int* __restrict__ qlist, int* __restrict__ islot) {
    __shared__ ShBQ sh;
    int tid = threadIdx.x;

    if (blockIdx.x < 32) {
        // ---------------- prep path ----------------
        int s = blockIdx.x;
        int gt = s * 256 + tid;            // 8192 total
        {   // W2 pack: B-frag lane L holds B[k=(L>>4)*8+j][n=L&15]
            int j  = gt & 7;
            int L  = (gt >> 3) & 63;
            int ks = (gt >> 9) & 3;
            int t4 = gt >> 11;
            int k = ks * 32 + (L >> 4) * 8 + j;
            int n = t4 * 16 + (L & 15);
            w2b[gt] = f2h_bits(W2[k * 64 + n]);
        }
        int base = s << 10;
        for (int i = tid; i < 1024; i += 256) sh.pm.cntS[i] = 0;
        __syncthreads();
        for (int ql = tid; ql < 1024; ql += 256) {
            float2 p = *(const float2*)&pos[2 * (base + ql)];
            int row = min(max((int)(p.y * 32.0f), 0), 31);
            int col = min(max((int)(p.x * 32.0f), 0), 31);
            int pixl = row * 32 + col;
            sh.pm.pixOf[ql] = pixl;
            atomicAdd(&sh.pm.cntS[pixl], 1);
        }
        __syncthreads();
        int a0 = sh.pm.cntS[4 * tid], a1 = sh.pm.cntS[4 * tid + 1];
        int a2 = sh.pm.cntS[4 * tid + 2], a3 = sh.pm.cntS[4 * tid + 3];
        int tsum = a0 + a1 + a2 + a3;
        int lane = tid & 63, wv = tid >> 6;
        int v = tsum;
        for (int o = 1; o < 64; o <<= 1) { int u = __shfl_up(v, o); if (lane >= o) v += u; }
        if (lane == 63) sh.pm.wtot[wv] = v;
        __syncthreads();
        int wbase = 0;
        for (int w = 0; w < wv; ++w) wbase += sh.pm.wtot[w];
        int excl = wbase + v - tsum;
        sh.pm.preS[4 * tid] = excl;
        sh.pm.preS[4 * tid + 1] = excl + a0;
        sh.pm.preS[4 * tid + 2] = excl + a0 + a1;
        sh.pm.preS[4 * tid + 3] = excl + a0 + a1 + a2;
        __syncthreads();
        for (int i = tid; i < 1024; i += 256) sh.pm.offS[i] = sh.pm.preS[i];
        __syncthreads();
        for (int ql = tid; ql < 1024; ql += 256) {
            int p = sh.pm.pixOf[ql];
            int slot = atomicAdd(&sh.pm.offS[p], 1);
            qlist[base + slot] = base + ql;
            islot[base + ql] = base + slot;
        }
        for (int i = tid; i < 1024; i += 256) {
            qcnt[base + i] = sh.pm.cntS[i];
            qstart[base + i] = base + sh.pm.preS[i];
        }
        return;
    }

    // ---------------- ball query path ----------------
    int bqid = blockIdx.x - 32;        // 0..1023
    int wave = tid >> 6, lane = tid & 63;
    int s = bqid >> 5;                 // sample
    int chunk = bqid & 31;             // 32 chunks of 32 queries
    int base = s << 10;
    for (int i = tid; i < 1024; i += 256) sh.bq.poss[i] = *(const float2*)&pos[2 * (base + i)];
    for (int i = tid; i < 1024; i += 256) { sh.bq.accd[i] = 0.0f; sh.bq.accx[i] = 0.0f; sh.bq.accy[i] = 0.0f; }
    __syncthreads();
    float2 pr[16];
#pragma unroll
    for (int k = 0; k < 16; ++k) pr[k] = sh.bq.poss[k * 64 + lane];
    unsigned long long lb = (1ull << lane) - 1ull;   // bits below this lane

    float aD = 0, aE = 0, aF = 0;
    for (int qi = 0; qi < 8; ++qi) {
        int ql = chunk * 32 + wave * 8 + qi;
        int q = base + ql;
        float2 qp = sh.bq.poss[ql];
        int row = min(max((int)(qp.y * 32.0f), 0), 31);
        int col = min(max((int)(qp.x * 32.0f), 0), 31);
        int pixl = row * 32 + col;
        float2 tp = sh.bq.poss[pixl];
        int cnt = 0;
        __builtin_amdgcn_wave_barrier();
#pragma unroll
        for (int k = 0; k < 16; ++k) {
            float dx = pr[k].x - qp.x, dy = pr[k].y - qp.y;
            float d2 = __fadd_rn(__fmul_rn(dx, dx), __fmul_rn(dy, dy)); // no FMA contraction
            bool pred = (d2 <= 0.01f);
            unsigned long long mask = __ballot(pred);
            if (pred) {
                int slot = cnt + (int)__popcll(mask & lb);
                if (slot < 256)
                    sh.bq.cand[wave][slot] = ((unsigned long long)__float_as_uint(d2) << 32)
                                             | (unsigned int)(k * 64 + lane);
            }
            cnt += (int)__popcll(mask);
        }
        cnt = min(cnt, 256);
        __builtin_amdgcn_wave_barrier();
        int osel = 0;
        for (int cb = 0; cb < cnt; cb += 64) {
            int i = cb + lane;
            bool sel = false;
            int j = 0;
            if (i < cnt) {
                unsigned long long key = sh.bq.cand[wave][i];
                j = (int)(key & 0xffffffffu);
                if (cnt <= KNB) {
                    sel = (j != pixl);                 // all in-radius are top-K
                } else {
                    int rank = 0;
                    for (int t = 0; t < cnt; ++t) rank += (sh.bq.cand[wave][t] < key) ? 1 : 0;
                    sel = (rank < KNB) && (j != pixl); // top-K, then remove_self_loops
                }
            }
            unsigned long long mask = __ballot(sel);
            if (sel) {
                int slot = osel + (int)__popcll(mask & lb);
                nbrs[q * KNB + slot] = base + j;
                float rx = sh.bq.poss[j].x - tp.x, ry = sh.bq.poss[j].y - tp.y;
                aD += rx * rx; aE += rx * ry; aF += ry * ry;
                atomicAdd(&sh.bq.accd[j], 1.0f);
                atomicAdd(&sh.bq.accx[j], tp.x);
                atomicAdd(&sh.bq.accy[j], tp.y);
            }
            osel += (int)__popcll(mask);
        }
        if (lane == 0) nbr_cnt[q] = osel;
    }
#pragma unroll
    for (int o = 1; o < 64; o <<= 1) {
        aD += __shfl_xor(aD, o); aE += __shfl_xor(aE, o); aF += __shfl_xor(aF, o);
    }
    __syncthreads();
    float* pb = &bqpart[bqid * 3076];
    for (int i = tid; i < 1024; i += 256) {
        pb[i] = sh.bq.accd[i]; pb[1024 + i] = sh.bq.accx[i]; pb[2048 + i] = sh.bq.accy[i];
    }
    if (tid == 0) { pb[3072] = aD; pb[3073] = aE; pb[3074] = aF; }   // DEF tails, plain store
}

// ---------------- node GEMM1 + fused nodeagg + BN node-stats ----------------
// 256 blocks x 512 threads (8 waves); block = 128 nodes; lane owns f0=2l, f1=2l+1.
__launch_bounds__(512)
__global__ void k_y(const float* __restrict__ x, const float* __restrict__ W1,
                    const float* __restrict__ b1, const float* __restrict__ pos,
                    const float* __restrict__ bqpart,
                    unsigned int* __restrict__ yb, float* __restrict__ partials) {
    __shared__ float w1s[64 * 128];
    __shared__ float stage[8][512];
    __shared__ float lsum[515];
    __shared__ float degS[128], stxS[128], styS[128];
    int tid = threadIdx.x;
    int nblock = blockIdx.x * 128;
    for (int i = tid; i < 64 * 128; i += 512) w1s[i] = W1[i];
    for (int i = tid; i < 515; i += 512) lsum[i] = 0.0f;
    if (tid < 128) {                       // fused nodeagg: 32 chunk partials
        int n = nblock + tid;
        int s = n >> 10, off = n & 1023;
        const float* pb = &bqpart[(s * 32) * 3076];
        float d = 0, xx = 0, yy = 0;
        for (int j = 0; j < 32; ++j) {
            d  += pb[j * 3076 + off];
            xx += pb[j * 3076 + 1024 + off];
            yy += pb[j * 3076 + 2048 + off];
        }
        degS[tid] = d; stxS[tid] = xx; styS[tid] = yy;
    }
    __syncthreads();
    int wave = tid >> 6, lane = tid & 63;
    int f0 = 2 * lane, f1 = 2 * lane + 1;
    float b10 = b1[f0], b11 = b1[f1];
    float* st = &stage[wave][0];
    float P0 = 0, Q0 = 0, R0 = 0, S0 = 0, P1 = 0, Q1 = 0, R1 = 0, S1 = 0;
    float sB = 0, sC = 0, sDeg = 0;

    for (int it = 0; it < 2; ++it) {
        int nbase = nblock + (wave * 2 + it) * 8;
        __builtin_amdgcn_wave_barrier();
#pragma unroll
        for (int mm = 0; mm < 8; ++mm)
            st[mm * 64 + lane] = x[(nbase + mm) * 64 + lane];
        __builtin_amdgcn_wave_barrier();
        float z0[8], z1[8];
#pragma unroll
        for (int mm = 0; mm < 8; ++mm) { z0[mm] = b10; z1[mm] = b11; }
        for (int k4 = 0; k4 < 16; ++k4) {
            float2 wv0 = *(const float2*)&w1s[(k4 * 4 + 0) * 128 + f0];
            float2 wv1 = *(const float2*)&w1s[(k4 * 4 + 1) * 128 + f0];
            float2 wv2 = *(const float2*)&w1s[(k4 * 4 + 2) * 128 + f0];
            float2 wv3 = *(const float2*)&w1s[(k4 * 4 + 3) * 128 + f0];
#pragma unroll
            for (int mm = 0; mm < 8; ++mm) {
                float4 mk = *(const float4*)&st[mm * 64 + k4 * 4];
                z0[mm] += mk.x * wv0.x + mk.y * wv1.x + mk.z * wv2.x + mk.w * wv3.x;
                z1[mm] += mk.x * wv0.y + mk.y * wv1.y + mk.z * wv2.y + mk.w * wv3.y;
            }
        }
#pragma unroll
        for (int mm = 0; mm < 8; ++mm) {
            int n = nbase + mm;
            int li = n - nblock;
            float dg = degS[li];
            float wgt = 1.0f + dg;
            float Bn = dg * pos[2 * n]     - stxS[li];
            float Cn = dg * pos[2 * n + 1] - styS[li];
            float a = z0[mm], bq = z1[mm];
            P0 += wgt * a;  Q0 += wgt * a * a;  R0 += a * Bn;  S0 += a * Cn;
            P1 += wgt * bq; Q1 += wgt * bq * bq; R1 += bq * Bn; S1 += bq * Cn;
            sB += Bn; sC += Cn; sDeg += dg;
            yb[n * 64 + lane] = pack_bf2(a, bq);
        }
        __builtin_amdgcn_wave_barrier();
    }
    atomicAdd(&lsum[f0], P0);        atomicAdd(&lsum[f1], P1);
    atomicAdd(&lsum[128 + f0], Q0);  atomicAdd(&lsum[128 + f1], Q1);
    atomicAdd(&lsum[256 + f0], R0);  atomicAdd(&lsum[256 + f1], R1);
    atomicAdd(&lsum[384 + f0], S0);  atomicAdd(&lsum[384 + f1], S1);
    if (lane == 0) {
        atomicAdd(&lsum[512], sB);
        atomicAdd(&lsum[513], sC);
        atomicAdd(&lsum[514], sDeg);
    }
    __syncthreads();
    for (int i = tid; i < 515; i += 512) partials[blockIdx.x * 516 + i] = lsum[i];
}

// --------------------------- finalize BN scale/shift ------------------------
__global__ void k_finalize(const float* __restrict__ gamma, const float* __restrict__ beta,
                           const float* __restrict__ W1, const float* __restrict__ partials,
                           const float* __restrict__ bqpart, float* __restrict__ scsh) {
    __shared__ float red[515];
    __shared__ float sDEF[3];
    int tid = threadIdx.x;    // 256
    if (tid < 3) sDEF[tid] = 0.0f;
    for (int i = tid; i < 515; i += 256) {
        float s = 0;
        for (int b = 0; b < 256; ++b) s += partials[b * 516 + i];
        red[i] = s;
    }
    __syncthreads();
    {   // sum the 1024 per-block DEF tails
        float td = 0, te = 0, tf = 0;
        for (int b = tid; b < 1024; b += 256) {
            const float* pb = &bqpart[b * 3076 + 3072];
            td += pb[0]; te += pb[1]; tf += pb[2];
        }
        atomicAdd(&sDEF[0], td); atomicAdd(&sDEF[1], te); atomicAdd(&sDEF[2], tf);
    }
    __syncthreads();
    if (tid < 128) {
        int f = tid;
        float P = red[f], Q = red[128 + f], R = red[256 + f], S = red[384 + f];
        float SB = red[512], SC = red[513], SDeg = red[514];
        float u = W1[8192 + f], v = W1[8320 + f];
        float cntv = 32768.0f + SDeg;
        float mean = (P + u * SB + v * SC) / cntv;
        float E2 = (Q + 2.0f * u * R + 2.0f * v * S
                    + u * u * sDEF[0] + 2.0f * u * v * sDEF[1] + v * v * sDEF[2]) / cntv;
        float var = E2 - mean * mean;
        float sc = gamma[f] / sqrtf(var + BN_EPS);
        scsh[f] = sc;
        scsh[128 + f] = beta[f] - mean * sc;
    }
}

// ---------- self pass (MFMA f16) + w/shp precompute (fp16) ------------------
__launch_bounds__(256)
__global__ void k_self(const unsigned int* __restrict__ yb, const float* __restrict__ pos,
                       const float* __restrict__ W1, const float* __restrict__ scsh,
                       const unsigned short* __restrict__ w2b, const float* __restrict__ b2,
                       const int* __restrict__ qcnt,
                       unsigned int* __restrict__ wbuf, unsigned int* __restrict__ shpbuf,
                       float* __restrict__ selfbuf, float* __restrict__ out) {
    __shared__ unsigned short hbuf[4][16 * 136];   // 272 B row stride
    int tid = threadIdx.x, wave = tid >> 6, lane = tid & 63;
    unsigned short* hb = hbuf[wave];
    half8 bfrag[4][4];
#pragma unroll
    for (int t = 0; t < 4; ++t)
#pragma unroll
        for (int ks = 0; ks < 4; ++ks)
            bfrag[t][ks] = *(const half8*)&w2b[((t * 4 + ks) * 64 + lane) * 8];
    int f0 = 2 * lane;
    float sc0 = scsh[f0],     sh0 = scsh[128 + f0];
    float sc1 = scsh[f0 + 1], sh1 = scsh[129 + f0];
    float u0 = W1[8192 + f0], v0 = W1[8320 + f0];
    float u1 = W1[8193 + f0], v1 = W1[8321 + f0];
    float b2v0 = b2[(lane & 15)],      b2v1 = b2[16 + (lane & 15)];
    float b2v2 = b2[32 + (lane & 15)], b2v3 = b2[48 + (lane & 15)];

    int nbase = (blockIdx.x * 4 + wave) * 16;
#pragma unroll
    for (int c = 0; c < 2; ++c) {
        unsigned int yw[8];
#pragma unroll
        for (int j = 0; j < 8; ++j)
            yw[j] = yb[(nbase + c * 8 + j) * 64 + lane];
#pragma unroll
        for (int j = 0; j < 8; ++j) {
            int e = c * 8 + j;
            int nn = nbase + e;
            float y0 = bf_lo(yw[j]), y1 = bf_hi(yw[j]);
            float h0 = fmaxf(y0 * sc0 + sh0, 0.0f);
            float h1 = fmaxf(y1 * sc1 + sh1, 0.0f);
            *(unsigned int*)&hb[e * 136 + f0] = pack_h2(h0, h1);
            float px = pos[2 * nn], py = pos[2 * nn + 1];
            float ts0 = (px * u0 + py * v0) * sc0;
            float ts1 = (px * u1 + py * v1) * sc1;
            wbuf[nn * 64 + lane]   = pack_h2(y0 * sc0 + ts0, y1 * sc1 + ts1);
            shpbuf[nn * 64 + lane] = pack_h2(sh0 - ts0, sh1 - ts1);
        }
    }
    __builtin_amdgcn_wave_barrier();
    floatx4 acc0 = {0,0,0,0}, acc1 = {0,0,0,0}, acc2 = {0,0,0,0}, acc3 = {0,0,0,0};
#pragma unroll
    for (int ks = 0; ks < 4; ++ks) {
        half8 a = *(const half8*)&hb[(lane & 15) * 136 + ks * 32 + (lane >> 4) * 8];
        acc0 = __builtin_amdgcn_mfma_f32_16x16x32_f16(a, bfrag[0][ks], acc0, 0, 0, 0);
        acc1 = __builtin_amdgcn_mfma_f32_16x16x32_f16(a, bfrag[1][ks], acc1, 0, 0, 0);
        acc2 = __builtin_amdgcn_mfma_f32_16x16x32_f16(a, bfrag[2][ks], acc2, 0, 0, 0);
        acc3 = __builtin_amdgcn_mfma_f32_16x16x32_f16(a, bfrag[3][ks], acc3, 0, 0, 0);
    }
    int nrow = nbase + (lane >> 4) * 4;
#pragma unroll
    for (int r = 0; r < 4; ++r) {
        int n = nrow + r;
        float o0 = acc0[r] + b2v0, o1 = acc1[r] + b2v1;
        float o2 = acc2[r] + b2v2, o3 = acc3[r] + b2v3;
        selfbuf[n * 64 + (lane & 15)]      = o0;   // contiguous copy for k_gather
        selfbuf[n * 64 + 16 + (lane & 15)] = o1;
        selfbuf[n * 64 + 32 + (lane & 15)] = o2;
        selfbuf[n * 64 + 48 + (lane & 15)] = o3;
        if (qcnt[n] == 0) {                 // k_gather overwrites qcnt>0 nodes
            int obase = (n >> 10) * 65536 + (n & 1023);
            out[obase + ((lane & 15)) * 1024]      = o0;
            out[obase + (16 + (lane & 15)) * 1024] = o1;
            out[obase + (32 + (lane & 15)) * 1024] = o2;
            out[obase + (48 + (lane & 15)) * 1024] = o3;
        }
    }
}

// ---------- neighbor pass: LDS-free; both tiles' gathers issued up-front ----
__launch_bounds__(256)
__global__ void k_out(const unsigned int* __restrict__ wbuf,
                      const unsigned int* __restrict__ shpbuf,
                      const float* __restrict__ pos,
                      const unsigned short* __restrict__ w2b, const float* __restrict__ b2,
                      const int* __restrict__ nbrs, const int* __restrict__ nbr_cnt,
                      const int* __restrict__ islot, float* __restrict__ scratch) {
    int tid = threadIdx.x, wave = tid >> 6, lane = tid & 63;
    half8 bfrag[4][4];
#pragma unroll
    for (int t = 0; t < 4; ++t)
#pragma unroll
        for (int ks = 0; ks < 4; ++ks)
            bfrag[t][ks] = *(const half8*)&w2b[((t * 4 + ks) * 64 + lane) * 8];
    float b2l = b2[lane];
    int em = lane & 15;                  // edge-in-tile this lane's A-frag covers
    int koff = (lane >> 4) * 4;          // dword offset of this lane's 8 features
    int wid = blockIdx.x * 4 + wave;     // 16384 waves, 2 queries each

    for (int qi = 0; qi < 2; ++qi) {
        int q = wid * 2 + qi;
        int m = nbr_cnt[q];              // m <= 32
        int b = q >> 10;
        float om0[4], om1[4], om2[4], om3[4];
#pragma unroll
        for (int r = 0; r < 4; ++r) { om0[r] = -INFINITY; om1[r] = -INFINITY; om2[r] = -INFINITY; om3[r] = -INFINITY; }
        float qx = pos[2 * q], qy = pos[2 * q + 1];
        int row = min(max((int)(qy * 32.0f), 0), 31);
        int col = min(max((int)(qx * 32.0f), 0), 31);
        int pixq = (b << 10) + row * 32 + col;

        if (m > 0) {
            // per-query shp (fp16 pairs), 4 uint4 = this lane's 32 features
            uint4 sv[4];
#pragma unroll
            for (int ks = 0; ks < 4; ++ks)
                sv[ks] = *(const uint4*)&shpbuf[pixq * 64 + ks * 16 + koff];
            int nv = (lane < m) ? nbrs[q * KNB + lane] : 0;
            // both tiles' sources + ALL gathers issued before any MFMA
            int src0 = __shfl(nv, em);
            int src1 = __shfl(nv, 16 + em);
            bool two = (m > 16);
            uint4 g0[4], g1[4];
            const unsigned int* wp0 = &wbuf[src0 * 64 + koff];
#pragma unroll
            for (int ks = 0; ks < 4; ++ks) g0[ks] = *(const uint4*)&wp0[ks * 16];
            if (two) {
                const unsigned int* wp1 = &wbuf[src1 * 64 + koff];
#pragma unroll
                for (int ks = 0; ks < 4; ++ks) g1[ks] = *(const uint4*)&wp1[ks * 16];
            }
            int rowb = (lane >> 4) * 4;
            // ---- tile 0 ----
            {
                floatx4 a0 = {0,0,0,0}, a1 = {0,0,0,0}, a2 = {0,0,0,0}, a3 = {0,0,0,0};
#pragma unroll
                for (int ks = 0; ks < 4; ++ks) {
                    union { unsigned int u[4]; half8 h8; } af;
#pragma unroll
                    for (int qd = 0; qd < 4; ++qd) {
                        unsigned int wd = (qd == 0) ? g0[ks].x : (qd == 1) ? g0[ks].y : (qd == 2) ? g0[ks].z : g0[ks].w;
                        unsigned int sd = (qd == 0) ? sv[ks].x : (qd == 1) ? sv[ks].y : (qd == 2) ? sv[ks].z : sv[ks].w;
                        half2v wh = *reinterpret_cast<half2v*>(&wd);
                        half2v shh = *reinterpret_cast<half2v*>(&sd);
                        half2v zz = { (_Float16)0.0f, (_Float16)0.0f };
                        half2v hh = __builtin_elementwise_max(wh + shh, zz);
                        af.u[qd] = *reinterpret_cast<unsigned int*>(&hh);
                    }
                    a0 = __builtin_amdgcn_mfma_f32_16x16x32_f16(af.h8, bfrag[0][ks], a0, 0, 0, 0);
                    a1 = __builtin_amdgcn_mfma_f32_16x16x32_f16(af.h8, bfrag[1][ks], a1, 0, 0, 0);
                    a2 = __builtin_amdgcn_mfma_f32_16x16x32_f16(af.h8, bfrag[2][ks], a2, 0, 0, 0);
                    a3 = __builtin_amdgcn_mfma_f32_16x16x32_f16(af.h8, bfrag[3][ks], a3, 0, 0, 0);
                }
#pragma unroll
                for (int r = 0; r < 4; ++r) {
                    if (rowb + r < m) {
                        om0[r] = fmaxf(om0[r], a0[r]);
                        om1[r] = fmaxf(om1[r], a1[r]);
                        om2[r] = fmaxf(om2[r], a2[r]);
                        om3[r] = fmaxf(om3[r], a3[r]);
                    }
                }
            }
            // ---- tile 1 ----
            if (two) {
                floatx4 a0 = {0,0,0,0}, a1 = {0,0,0,0}, a2 = {0,0,0,0}, a3 = {0,0,0,0};
#pragma unroll
                for (int ks = 0; ks < 4; ++ks) {
                    union { unsigned int u[4]; half8 h8; } af;
#pragma unroll
                    for (int qd = 0; qd < 4; ++qd) {
                        unsigned int wd = (qd == 0) ? g1[ks].x : (qd == 1) ? g1[ks].y : (qd == 2) ? g1[ks].z : g1[ks].w;
                        unsigned int sd = (qd == 0) ? sv[ks].x : (qd == 1) ? sv[ks].y : (qd == 2) ? sv[ks].z : sv[ks].w;
                        half2v wh = *reinterpret_cast<half2v*>(&wd);
                        half2v shh = *reinterpret_cast<half2v*>(&sd);
                        half2v zz = { (_Float16)0.0f, (_Float16)0.0f };
                        half2v hh = __builtin_elementwise_max(wh + shh, zz);
                        af.u[qd] = *reinterpret_cast<unsigned int*>(&hh);
                    }
                    a0 = __builtin_amdgcn_mfma_f32_16x16x32_f16(af.h8, bfrag[0][ks], a0, 0, 0, 0);
                    a1 = __builtin_amdgcn_mfma_f32_16x16x32_f16(af.h8, bfrag[1][ks], a1, 0, 0, 0);
                    a2 = __builtin_amdgcn_mfma_f32_16x16x32_f16(af.h8, bfrag[2][ks], a2, 0, 0, 0);
                    a3 = __builtin_amdgcn_mfma_f32_16x16x32_f16(af.h8, bfrag[3][ks], a3, 0, 0, 0);
                }
#pragma unroll
                for (int r = 0; r < 4; ++r) {
                    int e = 16 + rowb + r;
                    if (e < m) {
                        om0[r] = fmaxf(om0[r], a0[r]);
                        om1[r] = fmaxf(om1[r], a1[r]);
                        om2[r] = fmaxf(om2[r], a2[r]);
                        om3[r] = fmaxf(om3[r], a3[r]);
                    }
                }
            }
        }
        float w0 = fmaxf(fmaxf(om0[0], om0[1]), fmaxf(om0[2], om0[3]));
        float w1 = fmaxf(fmaxf(om1[0], om1[1]), fmaxf(om1[2], om1[3]));
        float w2 = fmaxf(fmaxf(om2[0], om2[1]), fmaxf(om2[2], om2[3]));
        float w3 = fmaxf(fmaxf(om3[0], om3[1]), fmaxf(om3[2], om3[3]));
        w0 = fmaxf(w0, __shfl_xor(w0, 16)); w0 = fmaxf(w0, __shfl_xor(w0, 32));
        w1 = fmaxf(w1, __shfl_xor(w1, 16)); w1 = fmaxf(w1, __shfl_xor(w1, 32));
        w2 = fmaxf(w2, __shfl_xor(w2, 16)); w2 = fmaxf(w2, __shfl_xor(w2, 32));
        w3 = fmaxf(w3, __shfl_xor(w3, 16)); w3 = fmaxf(w3, __shfl_xor(w3, 32));
        int g4 = lane >> 4;   // feature = g4*16 + (lane&15) = lane
        float vf = (g4 == 0) ? w0 : (g4 == 1) ? w1 : (g4 == 2) ? w2 : w3;
        vf += b2l;            // m==0 -> -inf: ignored by k_gather's max
        scratch[islot[q] * 64 + lane] = vf;    // plain coalesced store, no atomics
    }
}

// ---------- gather: per pixel, max(self, contiguous query slots) ------------
__launch_bounds__(256)
__global__ void k_gather(const float* __restrict__ scratch, const float* __restrict__ selfbuf,
                         const int* __restrict__ qcnt, const int* __restrict__ qstart,
                         float* __restrict__ out) {
    int tid = threadIdx.x, wave = tid >> 6, lane = tid & 63;
    int n = blockIdx.x * 4 + wave;
    int c = qcnt[n];
    if (c == 0) return;                  // out written by k_self
    int qs = qstart[n];
    float v = selfbuf[n * 64 + lane];
    for (int i = 0; i < c; ++i)
        v = fmaxf(v, scratch[(qs + i) * 64 + lane]);
    out[(n >> 10) * 65536 + lane * 1024 + (n & 1023)] = v;
}

extern "C" void kernel_launch(void* const* d_in, const int* in_sizes, int n_in,
                              void* d_out, int out_size, void* d_ws, size_t ws_size,
                              hipStream_t stream) {
    const float* x     = (const float*)d_in[0];
    const float* pos   = (const float*)d_in[1];
    // d_in[2] = batch (unused: points are sorted, b = idx >> 10)
    const float* W1    = (const float*)d_in[3];
    const float* b1    = (const float*)d_in[4];
    const float* gamma = (const float*)d_in[5];
    const float* beta  = (const float*)d_in[6];
    const float* W2    = (const float*)d_in[7];
    const float* b2    = (const float*)d_in[8];
    float* out = (float*)d_out;
    char* ws = (char*)d_ws;
    int*   nbrs     = (int*)(ws + WS_NBRS);
    int*   nbr_cnt  = (int*)(ws + WS_NBRCNT);
    float* scsh     = (float*)(ws + WS_SCSH);
    unsigned short* w2b = (unsigned short*)(ws + WS_W2B);
    float* partials = (float*)(ws + WS_PART);
    unsigned int* yb = (unsigned int*)(ws + WS_Y);
    float* scratch  = (float*)(ws + WS_SCRATCH);        // overlays yb (dead after k_self)
    unsigned int* wbuf = (unsigned int*)(ws + WS_WB);
    int* qcnt   = (int*)(ws + WS_QCNT);
    int* qstart = (int*)(ws + WS_QSTART);
    int* qlist  = (int*)(ws + WS_QLIST);
    int* islot  = (int*)(ws + WS_ISLOT);
    float* selfbuf = (float*)(ws + WS_SELF);
    unsigned int* shpbuf = (unsigned int*)(ws + WS_SHP);
    float* bqpart   = (float*)(ws + WS_BQPART);         // overlays self+shp (dead before k_self)

    k_bq<<<1056, 256, 0, stream>>>(pos, nbrs, nbr_cnt, bqpart, W2, w2b,
                                   qcnt, qstart, qlist, islot);
    k_y<<<256, 512, 0, stream>>>(x, W1, b1, pos, bqpart, yb, partials);
    k_finalize<<<1, 256, 0, stream>>>(gamma, beta, W1, partials, bqpart, scsh);
    k_self<<<NPTS / 64, 256, 0, stream>>>(yb, pos, W1, scsh, w2b, b2, qcnt,
                                          wbuf, shpbuf, selfbuf, out);
    k_out<<<NPTS / 8, 256, 0, stream>>>(wbuf, shpbuf, pos, w2b, b2,
                                        nbrs, nbr_cnt, islot, scratch);
    k_gather<<<NPTS / 4, 256, 0, stream>>>(scratch, selfbuf, qcnt, qstart, out);
}